// Round 1
// baseline (578240.723 us; speedup 1.0000x reference)
//
#include <hip/hip_runtime.h>
#include <hip/hip_cooperative_groups.h>
#include <math.h>

namespace cg = cooperative_groups;

#define TT 512
#define DPOI 256
#define DIN 260
#define DHID 356
#define DOUTD 512
#define G3 1536

// GRU partition: 32 worker blocks x 1024 threads, 16 hidden units per block.
// Workers are bids with (bid & 7) == 0 out of a 256-block cooperative grid:
// under MI355X round-robin dispatch (xcd = bid % 8) all workers share XCD 0,
// whose L2 is coherent between them -> comm via sc0-only (L1-bypass) ops.
// Placement is RUNTIME-VERIFIED via HW_REG_XCC_ID; mismatch falls back to the
// LLC-scope (sc0 sc1) path, which is correct under any placement.
#define GB 32
#define HU (DOUTD / GB)      // 16 hidden units per block
#define NR (3 * HU)          // 48 w_hh rows per block (bf16 LDS: 48 KB)
#define GRID_TOTAL 256

// ---------------- feature kernel ----------------
__global__ void feat_kernel(const int* __restrict__ idx, const float* __restrict__ timef,
                            const float* __restrict__ latlon, float* __restrict__ feat) {
    int i = threadIdx.x;
    if (i >= TT) return;
    float t = fminf(fmaxf(timef[i], 0.f), 1.f);
    const float TWO_PI = 6.28318530717958647692f;
    float s = sinf(TWO_PI * t);
    float c = cosf(TWO_PI * t);
    float dt_h = 0.f, dd = 0.f;
    if (i > 0) {
        float tp = fminf(fmaxf(timef[i - 1], 0.f), 1.f);
        float d = t - tp;
        d = d - floorf(d);          // jnp.mod(x, 1.0)
        dt_h = d * 24.f;
        int i0 = idx[i - 1], i1 = idx[i];
        float la0 = latlon[2 * (size_t)i0], lo0 = latlon[2 * (size_t)i0 + 1];
        float la1 = latlon[2 * (size_t)i1], lo1 = latlon[2 * (size_t)i1 + 1];
        const float D2R = 0.01745329251994329577f;
        float lat1 = fminf(fmaxf(la0, -90.f), 90.f) * D2R;
        float lon1 = fminf(fmaxf(lo0, -180.f), 180.f) * D2R;
        float lat2 = fminf(fmaxf(la1, -90.f), 90.f) * D2R;
        float lon2 = fminf(fmaxf(lo1, -180.f), 180.f) * D2R;
        float dlat = (lat2 - lat1) * 0.5f, dlon = (lon2 - lon1) * 0.5f;
        float sdlat = sinf(dlat), sdlon = sinf(dlon);
        float a = sdlat * sdlat +
                  fminf(fmaxf(cosf(lat1), -1.f), 1.f) * fminf(fmaxf(cosf(lat2), -1.f), 1.f) * sdlon * sdlon;
        float aa = fminf(fmaxf(a, 0.f), 1.f);
        float bb = fminf(fmaxf(1.f - a, 1e-12f), 1.f);
        float cc = 2.f * atan2f(sqrtf(aa), sqrtf(bb));
        dd = 6371.0088f * cc;
    }
    feat[4 * i + 0] = s;
    feat[4 * i + 1] = c;
    feat[4 * i + 2] = log1pf(dt_h);
    feat[4 * i + 3] = log1pf(dd);
}

// ---------------- gather + layernorm ----------------
__global__ void ln_kernel(const int* __restrict__ idx, const float* __restrict__ emb,
                          const float* __restrict__ feat, const float* __restrict__ lnw,
                          const float* __restrict__ lnb, float* __restrict__ xn) {
    int t = blockIdx.x;
    int tid = threadIdx.x;           // 256 threads
    int wave = tid >> 6, lane = tid & 63;
    const float* row = emb + (size_t)idx[t] * DPOI;
    float v0 = row[tid];
    float v1 = (tid < 4) ? feat[4 * t + tid] : 0.f;

    __shared__ float red[4];
    __shared__ float mu_s, rs_s;

    float s = v0 + v1;
    for (int o = 32; o; o >>= 1) s += __shfl_down(s, o, 64);
    if (lane == 0) red[wave] = s;
    __syncthreads();
    if (tid == 0) mu_s = (red[0] + red[1] + red[2] + red[3]) * (1.f / 260.f);
    __syncthreads();
    float mu = mu_s;
    float d0 = v0 - mu;
    float d1 = (tid < 4) ? (v1 - mu) : 0.f;
    float sq = d0 * d0 + d1 * d1;
    for (int o = 32; o; o >>= 1) sq += __shfl_down(sq, o, 64);
    __syncthreads();
    if (lane == 0) red[wave] = sq;
    __syncthreads();
    if (tid == 0) {
        float var = (red[0] + red[1] + red[2] + red[3]) * (1.f / 260.f);
        rs_s = rsqrtf(var + 1e-5f);
    }
    __syncthreads();
    float rs = rs_s;
    xn[t * DIN + tid] = d0 * rs * lnw[tid] + lnb[tid];
    if (tid < 4)
        xn[t * DIN + 256 + tid] = d1 * rs * lnw[256 + tid] + lnb[256 + tid];
}

// ---------------- x @ w1 + b1, gelu ----------------
__global__ void mlp1_kernel(const float* __restrict__ xn, const float* __restrict__ w1,
                            const float* __restrict__ b1, float* __restrict__ h1) {
    int t = blockIdx.x, j = threadIdx.x;   // 384 threads
    __shared__ float xl[DIN];
    for (int k = threadIdx.x; k < DIN; k += blockDim.x) xl[k] = xn[t * DIN + k];
    __syncthreads();
    if (j < DHID) {
        float acc = b1[j];
        #pragma unroll 4
        for (int k = 0; k < DIN; ++k) acc = fmaf(xl[k], w1[k * DHID + j], acc);
        float g = 0.5f * acc * (1.f + erff(acc * 0.70710678118654752440f));
        h1[t * DHID + j] = g;
    }
}

// ---------------- h1 @ w2 + b2 ----------------
__global__ void mlp2_kernel(const float* __restrict__ h1, const float* __restrict__ w2,
                            const float* __restrict__ b2, float* __restrict__ x2) {
    int t = blockIdx.x, j = threadIdx.x;   // 256 threads
    __shared__ float xl[DHID];
    for (int k = threadIdx.x; k < DHID; k += blockDim.x) xl[k] = h1[t * DHID + k];
    __syncthreads();
    float acc = b2[j];
    #pragma unroll 4
    for (int k = 0; k < DHID; ++k) acc = fmaf(xl[k], w2[k * DPOI + j], acc);
    x2[t * DPOI + j] = acc;
}

// ---------------- gi = x2 @ w_ih.T + b_ih ----------------
__global__ void gi_kernel(const float* __restrict__ x2, const float* __restrict__ wih,
                          const float* __restrict__ bih, float* __restrict__ gi) {
    int t = blockIdx.x;
    int tid = threadIdx.x;   // 256
    int wave = tid >> 6, lane = tid & 63;
    float4 xv = ((const float4*)(x2 + (size_t)t * DPOI))[lane];
    for (int r = wave; r < G3; r += 4) {
        float4 wv = ((const float4*)(wih + (size_t)r * DPOI))[lane];
        float s = xv.x * wv.x + xv.y * wv.y + xv.z * wv.z + xv.w * wv.w;
        for (int o = 32; o; o >>= 1) s += __shfl_down(s, o, 64);
        if (lane == 0) gi[(size_t)t * G3 + r] = s + bih[r];
    }
}

// ---------------- zero comm region (ctrl + hcomm tags) ----------------
__global__ void zero_kernel(uint4* __restrict__ p, int n16) {
    int i = blockIdx.x * blockDim.x + threadIdx.x;
    int stride = gridDim.x * blockDim.x;
    uint4 z; z.x = 0u; z.y = 0u; z.z = 0u; z.w = 0u;
    for (; i < n16; i += stride) p[i] = z;
}

// ---------------- comm primitives ----------------
// FAST: sc0 only -> bypass L1, served by the XCD-shared L2 (valid only when all
//       workers verified on the same XCD).
// SLOW: sc0 sc1 -> bypass L1+L2, served at the LLC / coherence fabric (valid
//       under any placement; same semantics as agent-scope relaxed atomics).
// 8-byte aligned single-instruction accesses are single-copy atomic, so each
// {f32 value, u32 step-tag} payload self-validates: no flags, no fences.
template<bool FAST>
__device__ __forceinline__ void comm_store8(unsigned long long* p, unsigned long long v) {
    if constexpr (FAST)
        asm volatile("global_store_dwordx2 %0, %1, off sc0" :: "v"(p), "v"(v) : "memory");
    else
        asm volatile("global_store_dwordx2 %0, %1, off sc0 sc1" :: "v"(p), "v"(v) : "memory");
}

template<bool FAST>
__device__ __forceinline__ unsigned long long comm_load8(const unsigned long long* p) {
    unsigned long long r;
    if constexpr (FAST)
        asm volatile("global_load_dwordx2 %0, %1, off sc0\n\ts_waitcnt vmcnt(0)"
                     : "=v"(r) : "v"(p) : "memory");
    else
        asm volatile("global_load_dwordx2 %0, %1, off sc0 sc1\n\ts_waitcnt vmcnt(0)"
                     : "=v"(r) : "v"(p) : "memory");
    return r;
}

// ---------------- GRU scan body (templated on comm path) ----------------
template<bool FAST>
__device__ __forceinline__ void gru_scan(const float* __restrict__ gi,
                                         unsigned long long* __restrict__ hcomm,
                                         float* __restrict__ hs,
                                         const unsigned short* __restrict__ wl,
                                         float* __restrict__ hprev,
                                         float* __restrict__ gsum,
                                         const float* __restrict__ bl,
                                         int b, int tid) {
    int wave = tid >> 6, lane = tid & 63;
    int jbase = b * HU;
    long budget = 2000000;               // lifetime spin budget: deadlock -> numeric fail
    const float4* hp4 = (const float4*)hprev;

    // gi prefetch registers (gate lanes only) — loaded one step ahead so the
    // L2 latency of the gi reads is hidden under the whole previous step.
    float gir = 0.f, giz = 0.f, gin = 0.f, hreg = 0.f;
    if (tid < HU) {
        int j = jbase + tid;
        gir = gi[j];
        giz = gi[DOUTD + j];
        gin = gi[2 * DOUTD + j];
    }

    for (int s = 0; s < TT; ++s) {
        if (s > 0) {
            // lanes 0..31 of wave w poll values v = 32w + lane (covers 2 producer
            // blocks per wave); own block's chunk is self-published through LDS.
            if (lane < 32) {
                int v = (wave << 5) + lane;
                bool own = (v >> 4) == b;
                const unsigned long long* ap = hcomm + (size_t)(s - 1) * DOUTD + v;
                unsigned long long p = 0;
                bool ok = own;
                while (true) {
                    if (!ok) {
                        p = comm_load8<FAST>(ap);
                        ok = ((unsigned)(p >> 32) == (unsigned)s);
                    }
                    if (__all(ok)) break;
                    if (--budget < 0) break;
                }
                if (!own) hprev[v] = __uint_as_float((unsigned)p);
            }
            __syncthreads();   // barrier A: full h_{s-1} in hprev
        }

        // matvec: 48 rows over 16 waves -> 3 rows/wave.
        // hprev: two conflict-free ds_read_b128 per lane, shared across rows.
        // w row: one conflict-free ds_read_b128 per lane (interleaved bf16 layout:
        // lane l holds k = 4l..4l+3 and 256+4l..256+4l+3).
        float4 ha = hp4[lane];
        float4 hb = hp4[64 + lane];
        #pragma unroll
        for (int rv = 0; rv < 3; ++rv) {
            int rr = wave * 3 + rv;
            uint4 wv = *(const uint4*)(wl + (rr << 9) + (lane << 3));
            float acc;
            acc = __uint_as_float(wv.x << 16) * ha.x;
            acc = fmaf(__uint_as_float(wv.x & 0xffff0000u), ha.y, acc);
            acc = fmaf(__uint_as_float(wv.y << 16), ha.z, acc);
            acc = fmaf(__uint_as_float(wv.y & 0xffff0000u), ha.w, acc);
            acc = fmaf(__uint_as_float(wv.z << 16), hb.x, acc);
            acc = fmaf(__uint_as_float(wv.z & 0xffff0000u), hb.y, acc);
            acc = fmaf(__uint_as_float(wv.w << 16), hb.z, acc);
            acc = fmaf(__uint_as_float(wv.w & 0xffff0000u), hb.w, acc);
            for (int o = 32; o; o >>= 1) acc += __shfl_down(acc, o, 64);
            if (lane == 0) gsum[rr] = acc + bl[rr];
        }
        __syncthreads();       // barrier B: gsum complete; all hprev reads done

        if (tid < HU) {        // wave 0, lanes 0..15: gates + publish
            int j = jbase + tid;
            float gr  = gir + gsum[tid];
            float gz  = giz + gsum[HU + tid];
            float ghn = gsum[2 * HU + tid];
            float r = 1.f / (1.f + expf(-gr));
            float z = 1.f / (1.f + expf(-gz));
            float n = tanhf(gin + r * ghn);
            float hn = (1.f - z) * n + z * hreg;
            hreg = hn;
            hs[(size_t)s * DOUTD + j] = hn;                      // plain store for attn
            unsigned long long pay = ((unsigned long long)(unsigned)(s + 1) << 32) |
                                     (unsigned long long)__float_as_uint(hn);
            comm_store8<FAST>(hcomm + (size_t)s * DOUTD + j, pay);
            hprev[j] = hn;     // self-publish own chunk (post-B; read post-A(s+1))
            if (s + 1 < TT) {  // prefetch next step's gi
                const float* gn = gi + (size_t)(s + 1) * G3;
                gir = gn[j]; giz = gn[DOUTD + j]; gin = gn[2 * DOUTD + j];
            }
        }
        // no producer drain, no flag store: payloads are self-validating
    }
}

// ---------------- GRU kernel ----------------
__global__ __launch_bounds__(1024)
void gru_fast_kernel(const float* __restrict__ gi, const float* __restrict__ whh,
                     const float* __restrict__ bhh, float* __restrict__ hs,
                     unsigned long long* __restrict__ hcomm,
                     unsigned long long* __restrict__ ctrl) {
    int bid = blockIdx.x;
    if (bid & 7) return;                 // workers: bid % 8 == 0 (round-robin -> one XCD)
    int b = bid >> 3;                    // 0..31
    int tid = threadIdx.x;               // 0..1023
    int jbase = b * HU;

    __shared__ unsigned short w[NR][DOUTD];   // 48*512*2 = 49152 B (interleaved layout)
    __shared__ float hprev[DOUTD];
    __shared__ float gsum[NR];
    __shared__ float bl[NR];
    __shared__ int xcds_sh[GB];
    __shared__ int fast_sh;

    // --- publish my XCD id (LLC scope; valid under any placement) ---
    if (tid == 0) {
        int xcd = __builtin_amdgcn_s_getreg((3 << 11) | 20) & 0xf;  // HW_REG_XCC_ID
        comm_store8<false>(&ctrl[b], (0xC0FFEEULL << 32) | (unsigned)xcd);
    }

    // --- stage weights: 48 rows, bf16 RNE, interleaved so each row is one
    //     conflict-free b128/lane: lane l <- k=4l..4l+3 then k=256+4l..256+4l+3 ---
    unsigned short* wl = &w[0][0];
    for (int e = tid; e < NR * DOUTD; e += 1024) {
        int rr = e >> 9, k = e & 511;
        int g = rr >> 4, jj = rr & 15;
        float v = whh[(size_t)(g * DOUTD + jbase + jj) * DOUTD + k];
        unsigned int u = __float_as_uint(v);
        u += 0x7fffu + ((u >> 16) & 1u);      // round-to-nearest-even
        int kk = (k < 256) ? (((k >> 2) << 3) | (k & 3))
                           : ((((k - 256) >> 2) << 3) | 4 | (k & 3));
        wl[(rr << 9) + kk] = (unsigned short)(u >> 16);
    }
    if (tid < NR) {
        int g = tid >> 4, jj = tid & 15;
        bl[tid] = bhh[g * DOUTD + jbase + jj];
    }
    if (tid < DOUTD) hprev[tid] = 0.f;
    __syncthreads();

    // --- block 0 collects all XCD ids and publishes the fast/slow decision ---
    if (b == 0) {
        if (tid < GB) {
            unsigned long long p = 0;
            long bud = 2000000;
            while (true) {
                p = comm_load8<false>(&ctrl[tid]);
                if ((unsigned)(p >> 32) == 0xC0FFEEu) break;
                if (--bud < 0) break;
            }
            xcds_sh[tid] = ((unsigned)(p >> 32) == 0xC0FFEEu) ? (int)(p & 0xf) : (-1 - tid);
        }
        __syncthreads();
        if (tid == 0) {
            int same = (xcds_sh[0] >= 0) ? 1 : 0;
            for (int i = 1; i < GB; ++i) same = (same && (xcds_sh[i] == xcds_sh[0])) ? 1 : 0;
            comm_store8<false>(&ctrl[40], (0xDEC1DEULL << 32) | (unsigned)same);
        }
    }
    // --- everyone (incl. block 0) reads the single decision word: uniform choice ---
    if (tid == 0) {
        unsigned long long p = 0;
        long bud = 4000000;
        while (true) {
            p = comm_load8<false>(&ctrl[40]);
            if ((unsigned)(p >> 32) == 0xDEC1DEu) break;
            if (--bud < 0) break;
        }
        fast_sh = ((unsigned)(p >> 32) == 0xDEC1DEu) ? (int)(p & 1) : 0;
    }
    __syncthreads();

    if (fast_sh)
        gru_scan<true>(gi, hcomm, hs, wl, hprev, gsum, bl, b, tid);
    else
        gru_scan<false>(gi, hcomm, hs, wl, hprev, gsum, bl, b, tid);
}

// ---------------- attention epilogue ----------------
__global__ void attn_kernel(const float* __restrict__ hs, const float* __restrict__ q,
                            const float* __restrict__ log_lam, float* __restrict__ out) {
    int tid = threadIdx.x;   // 512
    int wave = tid >> 6, lane = tid & 63;
    __shared__ float sc[TT];
    __shared__ float at[TT];
    __shared__ float red[8];
    __shared__ float red2[8];
    __shared__ float denom_s, mx_s;

    const float qscale = 0.04419417382415921757f;  // 1/sqrt(512)
    for (int r = wave; r < TT; r += 8) {
        float acc = 0.f;
        #pragma unroll
        for (int m = 0; m < 8; ++m) {
            int k = lane + 64 * m;
            acc = fmaf(hs[(size_t)r * DOUTD + k], q[k], acc);
        }
        for (int o = 32; o; o >>= 1) acc += __shfl_down(acc, o, 64);
        if (lane == 0) sc[r] = acc * qscale;
    }
    __syncthreads();
    float lam = fmaxf(expf(log_lam[0]), 1e-4f);
    float s_i = sc[tid] - lam * (float)(TT - 1 - tid);

    float mval = s_i;
    for (int o = 32; o; o >>= 1) mval = fmaxf(mval, __shfl_down(mval, o, 64));
    if (lane == 0) red[wave] = mval;
    __syncthreads();
    if (tid == 0) {
        float mm = red[0];
        for (int i = 1; i < 8; ++i) mm = fmaxf(mm, red[i]);
        mx_s = mm;
    }
    __syncthreads();
    float e = expf(s_i - mx_s);
    float ssum = e;
    for (int o = 32; o; o >>= 1) ssum += __shfl_down(ssum, o, 64);
    if (lane == 0) red2[wave] = ssum;
    __syncthreads();
    if (tid == 0) {
        float dsum = 0.f;
        for (int i = 0; i < 8; ++i) dsum += red2[i];
        denom_s = dsum;
    }
    __syncthreads();
    float attn = e / denom_s;
    out[DOUTD + tid] = attn;     // output 1: attn (T,)
    at[tid] = attn;
    __syncthreads();
    // summary[d]: coalesced across d for each row i
    float acc = 0.f;
    for (int i = 0; i < TT; ++i) acc = fmaf(at[i], hs[(size_t)i * DOUTD + tid], acc);
    out[tid] = acc;              // output 0: summary (1, 512)
}

extern "C" void kernel_launch(void* const* d_in, const int* in_sizes, int n_in,
                              void* d_out, int out_size, void* d_ws, size_t ws_size,
                              hipStream_t stream) {
    const int*   idx    = (const int*)d_in[0];
    const float* timef  = (const float*)d_in[1];
    const float* emb    = (const float*)d_in[2];
    const float* latlon = (const float*)d_in[3];
    const float* lnw    = (const float*)d_in[4];
    const float* lnb    = (const float*)d_in[5];
    const float* w1     = (const float*)d_in[6];
    const float* b1     = (const float*)d_in[7];
    const float* w2     = (const float*)d_in[8];
    const float* b2     = (const float*)d_in[9];
    const float* wih    = (const float*)d_in[10];  // (1536, 256)
    const float* whh    = (const float*)d_in[11];  // (1536, 512)
    const float* bih    = (const float*)d_in[12];  // (1536,)
    const float* bhh    = (const float*)d_in[13];  // (1536,)
    const float* q      = (const float*)d_in[14];
    const float* loglam = (const float*)d_in[15];
    float* out = (float*)d_out;

    unsigned long long* ctrl  = (unsigned long long*)d_ws;            // 64 slots (512 B)
    unsigned long long* hcomm = ctrl + 64;                            // 512*512 payloads (2 MB)
    float* feat = (float*)(hcomm + (size_t)TT * DOUTD);               // 2048
    float* xn   = feat + 2048;                                        // 512*260 = 133120
    float* h1   = xn + TT * DIN;                                      // 512*356 = 182272
    float* x2   = h1 + TT * DHID;                                     // 512*256 = 131072
    float* gi   = x2 + TT * DPOI;                                     // 512*1536 = 786432
    float* hs   = gi + (size_t)TT * G3;                               // 512*512 = 262144

    feat_kernel<<<1, TT, 0, stream>>>(idx, timef, latlon, feat);
    ln_kernel<<<TT, 256, 0, stream>>>(idx, emb, feat, lnw, lnb, xn);
    mlp1_kernel<<<TT, 384, 0, stream>>>(xn, w1, b1, h1);
    mlp2_kernel<<<TT, 256, 0, stream>>>(h1, w2, b2, x2);
    gi_kernel<<<TT, 256, 0, stream>>>(x2, wih, bih, gi);

    // zero ctrl + all hcomm step-tags (payloads self-validate via tag == step+1)
    int n16 = (int)((64 * 8 + (size_t)TT * DOUTD * 8) / 16);          // 131104 uint4
    zero_kernel<<<256, 512, 0, stream>>>((uint4*)d_ws, n16);

    void* gru_args[] = { (void*)&gi, (void*)&whh, (void*)&bhh, (void*)&hs,
                         (void*)&hcomm, (void*)&ctrl };
    hipLaunchCooperativeKernel((void*)gru_fast_kernel, dim3(GRID_TOTAL), dim3(1024),
                               gru_args, 0, stream);

    attn_kernel<<<1, TT, 0, stream>>>(hs, q, loglam, out);
}

// Round 2
// 1908.805 us; speedup vs baseline: 302.9333x; 302.9333x over previous
//
#include <hip/hip_runtime.h>
#include <hip/hip_cooperative_groups.h>
#include <math.h>

namespace cg = cooperative_groups;

#define TT 512
#define DPOI 256
#define DIN 260
#define DHID 356
#define DOUTD 512
#define G3 1536

// GRU partition: 32 worker blocks x 1024 threads, 16 hidden units per block.
// ALL cross-block comm is agent-scope relaxed atomics on 8-byte self-validating
// payloads {f32 h, u32 step-tag}: single-copy-atomic, reach the coherence point
// under ANY block->XCD placement (round-0-proven encoding). No flags, no
// producer-side drain, no dependent second load: one fabric hop per step.
#define GB 32
#define HU (DOUTD / GB)      // 16 hidden units per block
#define NR (3 * HU)          // 48 w_hh rows per block (bf16 LDS: 48 KB)

// ---------------- feature kernel ----------------
__global__ void feat_kernel(const int* __restrict__ idx, const float* __restrict__ timef,
                            const float* __restrict__ latlon, float* __restrict__ feat) {
    int i = threadIdx.x;
    if (i >= TT) return;
    float t = fminf(fmaxf(timef[i], 0.f), 1.f);
    const float TWO_PI = 6.28318530717958647692f;
    float s = sinf(TWO_PI * t);
    float c = cosf(TWO_PI * t);
    float dt_h = 0.f, dd = 0.f;
    if (i > 0) {
        float tp = fminf(fmaxf(timef[i - 1], 0.f), 1.f);
        float d = t - tp;
        d = d - floorf(d);          // jnp.mod(x, 1.0)
        dt_h = d * 24.f;
        int i0 = idx[i - 1], i1 = idx[i];
        float la0 = latlon[2 * (size_t)i0], lo0 = latlon[2 * (size_t)i0 + 1];
        float la1 = latlon[2 * (size_t)i1], lo1 = latlon[2 * (size_t)i1 + 1];
        const float D2R = 0.01745329251994329577f;
        float lat1 = fminf(fmaxf(la0, -90.f), 90.f) * D2R;
        float lon1 = fminf(fmaxf(lo0, -180.f), 180.f) * D2R;
        float lat2 = fminf(fmaxf(la1, -90.f), 90.f) * D2R;
        float lon2 = fminf(fmaxf(lo1, -180.f), 180.f) * D2R;
        float dlat = (lat2 - lat1) * 0.5f, dlon = (lon2 - lon1) * 0.5f;
        float sdlat = sinf(dlat), sdlon = sinf(dlon);
        float a = sdlat * sdlat +
                  fminf(fmaxf(cosf(lat1), -1.f), 1.f) * fminf(fmaxf(cosf(lat2), -1.f), 1.f) * sdlon * sdlon;
        float aa = fminf(fmaxf(a, 0.f), 1.f);
        float bb = fminf(fmaxf(1.f - a, 1e-12f), 1.f);
        float cc = 2.f * atan2f(sqrtf(aa), sqrtf(bb));
        dd = 6371.0088f * cc;
    }
    feat[4 * i + 0] = s;
    feat[4 * i + 1] = c;
    feat[4 * i + 2] = log1pf(dt_h);
    feat[4 * i + 3] = log1pf(dd);
}

// ---------------- gather + layernorm ----------------
__global__ void ln_kernel(const int* __restrict__ idx, const float* __restrict__ emb,
                          const float* __restrict__ feat, const float* __restrict__ lnw,
                          const float* __restrict__ lnb, float* __restrict__ xn) {
    int t = blockIdx.x;
    int tid = threadIdx.x;           // 256 threads
    int wave = tid >> 6, lane = tid & 63;
    const float* row = emb + (size_t)idx[t] * DPOI;
    float v0 = row[tid];
    float v1 = (tid < 4) ? feat[4 * t + tid] : 0.f;

    __shared__ float red[4];
    __shared__ float mu_s, rs_s;

    float s = v0 + v1;
    for (int o = 32; o; o >>= 1) s += __shfl_down(s, o, 64);
    if (lane == 0) red[wave] = s;
    __syncthreads();
    if (tid == 0) mu_s = (red[0] + red[1] + red[2] + red[3]) * (1.f / 260.f);
    __syncthreads();
    float mu = mu_s;
    float d0 = v0 - mu;
    float d1 = (tid < 4) ? (v1 - mu) : 0.f;
    float sq = d0 * d0 + d1 * d1;
    for (int o = 32; o; o >>= 1) sq += __shfl_down(sq, o, 64);
    __syncthreads();
    if (lane == 0) red[wave] = sq;
    __syncthreads();
    if (tid == 0) {
        float var = (red[0] + red[1] + red[2] + red[3]) * (1.f / 260.f);
        rs_s = rsqrtf(var + 1e-5f);
    }
    __syncthreads();
    float rs = rs_s;
    xn[t * DIN + tid] = d0 * rs * lnw[tid] + lnb[tid];
    if (tid < 4)
        xn[t * DIN + 256 + tid] = d1 * rs * lnw[256 + tid] + lnb[256 + tid];
}

// ---------------- x @ w1 + b1, gelu ----------------
__global__ void mlp1_kernel(const float* __restrict__ xn, const float* __restrict__ w1,
                            const float* __restrict__ b1, float* __restrict__ h1) {
    int t = blockIdx.x, j = threadIdx.x;   // 384 threads
    __shared__ float xl[DIN];
    for (int k = threadIdx.x; k < DIN; k += blockDim.x) xl[k] = xn[t * DIN + k];
    __syncthreads();
    if (j < DHID) {
        float acc = b1[j];
        #pragma unroll 4
        for (int k = 0; k < DIN; ++k) acc = fmaf(xl[k], w1[k * DHID + j], acc);
        float g = 0.5f * acc * (1.f + erff(acc * 0.70710678118654752440f));
        h1[t * DHID + j] = g;
    }
}

// ---------------- h1 @ w2 + b2 ----------------
__global__ void mlp2_kernel(const float* __restrict__ h1, const float* __restrict__ w2,
                            const float* __restrict__ b2, float* __restrict__ x2) {
    int t = blockIdx.x, j = threadIdx.x;   // 256 threads
    __shared__ float xl[DHID];
    for (int k = threadIdx.x; k < DHID; k += blockDim.x) xl[k] = h1[t * DHID + k];
    __syncthreads();
    float acc = b2[j];
    #pragma unroll 4
    for (int k = 0; k < DHID; ++k) acc = fmaf(xl[k], w2[k * DPOI + j], acc);
    x2[t * DPOI + j] = acc;
}

// ---------------- gi = x2 @ w_ih.T + b_ih ----------------
__global__ void gi_kernel(const float* __restrict__ x2, const float* __restrict__ wih,
                          const float* __restrict__ bih, float* __restrict__ gi) {
    int t = blockIdx.x;
    int tid = threadIdx.x;   // 256
    int wave = tid >> 6, lane = tid & 63;
    float4 xv = ((const float4*)(x2 + (size_t)t * DPOI))[lane];
    for (int r = wave; r < G3; r += 4) {
        float4 wv = ((const float4*)(wih + (size_t)r * DPOI))[lane];
        float s = xv.x * wv.x + xv.y * wv.y + xv.z * wv.z + xv.w * wv.w;
        for (int o = 32; o; o >>= 1) s += __shfl_down(s, o, 64);
        if (lane == 0) gi[(size_t)t * G3 + r] = s + bih[r];
    }
}

// ---------------- zero hcomm tags ----------------
// Plain stores are fine: the kernel-dispatch boundary is a system-scope
// release/acquire, so the zeros are globally visible before the GRU launches.
__global__ void zero_kernel(uint4* __restrict__ p, int n16) {
    int i = blockIdx.x * blockDim.x + threadIdx.x;
    int stride = gridDim.x * blockDim.x;
    uint4 z; z.x = 0u; z.y = 0u; z.z = 0u; z.w = 0u;
    for (; i < n16; i += stride) p[i] = z;
}

// ---------------- GRU scan: tagged-payload agent-scope protocol ----------------
__global__ __launch_bounds__(1024)
void gru_tag_kernel(const float* __restrict__ gi, const float* __restrict__ whh,
                    const float* __restrict__ bhh, float* __restrict__ hs,
                    unsigned long long* __restrict__ hcomm) {
    __shared__ unsigned short w[NR][DOUTD];   // 48*512*2 = 49152 B (interleaved layout)
    __shared__ float hprev[DOUTD];            // 2 KB
    __shared__ float gsum[NR];
    __shared__ float bl[NR];

    int b = blockIdx.x;        // 0..31
    int tid = threadIdx.x;     // 0..1023
    int wave = tid >> 6, lane = tid & 63;
    int jbase = b * HU;

    // --- stage weights: 48 rows, bf16 RNE, interleaved so each row is one
    //     conflict-free ds_read_b128/lane: lane l <- k=4l..4l+3, 256+4l..256+4l+3 ---
    unsigned short* wl = &w[0][0];
    for (int e = tid; e < NR * DOUTD; e += 1024) {
        int rr = e >> 9, k = e & 511;
        int g = rr >> 4, jj = rr & 15;
        float v = whh[(size_t)(g * DOUTD + jbase + jj) * DOUTD + k];
        unsigned int u = __float_as_uint(v);
        u += 0x7fffu + ((u >> 16) & 1u);      // round-to-nearest-even
        int kk = (k < 256) ? (((k >> 2) << 3) | (k & 3))
                           : ((((k - 256) >> 2) << 3) | 4 | (k & 3));
        wl[(rr << 9) + kk] = (unsigned short)(u >> 16);
    }
    if (tid < NR) {
        int g = tid >> 4, jj = tid & 15;
        bl[tid] = bhh[g * DOUTD + jbase + jj];
    }
    if (tid < DOUTD) hprev[tid] = 0.f;
    __syncthreads();

    const float4* hp4 = (const float4*)hprev;
    long budget = 2L * 1000 * 1000;   // lifetime spin budget: deadlock -> numeric fail

    // gi prefetch registers (gate lanes only), one step ahead; own h in register.
    float gir = 0.f, giz = 0.f, gin = 0.f, hreg = 0.f;
    if (tid < HU) {
        int j = jbase + tid;
        gir = gi[j];
        giz = gi[DOUTD + j];
        gin = gi[2 * DOUTD + j];
    }

    for (int s = 0; s < TT; ++s) {
        if (s > 0) {
            // lanes 0..31 of wave w poll payloads v = 32w + lane (512 pollers
            // cover all values); own block's chunk is self-published via LDS.
            if (lane < 32) {
                int v = (wave << 5) + lane;
                bool own = (v >> 4) == b;
                const unsigned long long* ap = hcomm + (size_t)(s - 1) * DOUTD + v;
                unsigned long long p = 0;
                bool ok = own;
                while (!__all(ok)) {
                    if (!ok) {
                        p = __hip_atomic_load(ap, __ATOMIC_RELAXED,
                                              __HIP_MEMORY_SCOPE_AGENT);
                        ok = ((unsigned)(p >> 32) == (unsigned)s);
                    }
                    if (--budget < 0) break;
                }
                if (!own) hprev[v] = __uint_as_float((unsigned)p);
            }
            __syncthreads();   // barrier A: full h_{s-1} in hprev
        }

        // matvec: 48 rows over 16 waves -> 3 rows/wave.
        // hprev: two conflict-free ds_read_b128; w row: one ds_read_b128/lane.
        float4 ha = hp4[lane];
        float4 hb = hp4[64 + lane];
        #pragma unroll
        for (int rv = 0; rv < 3; ++rv) {
            int rr = wave * 3 + rv;
            uint4 wv = *(const uint4*)(wl + (rr << 9) + (lane << 3));
            float acc;
            acc = __uint_as_float(wv.x << 16) * ha.x;
            acc = fmaf(__uint_as_float(wv.x & 0xffff0000u), ha.y, acc);
            acc = fmaf(__uint_as_float(wv.y << 16), ha.z, acc);
            acc = fmaf(__uint_as_float(wv.y & 0xffff0000u), ha.w, acc);
            acc = fmaf(__uint_as_float(wv.z << 16), hb.x, acc);
            acc = fmaf(__uint_as_float(wv.z & 0xffff0000u), hb.y, acc);
            acc = fmaf(__uint_as_float(wv.w << 16), hb.z, acc);
            acc = fmaf(__uint_as_float(wv.w & 0xffff0000u), hb.w, acc);
            for (int o = 32; o; o >>= 1) acc += __shfl_down(acc, o, 64);
            if (lane == 0) gsum[rr] = acc + bl[rr];
        }
        __syncthreads();       // barrier B: gsum complete; all hprev reads done

        if (tid < HU) {        // wave 0, lanes 0..15: gates + publish
            int j = jbase + tid;
            float gr  = gir + gsum[tid];
            float gz  = giz + gsum[HU + tid];
            float ghn = gsum[2 * HU + tid];
            float r = 1.f / (1.f + expf(-gr));
            float z = 1.f / (1.f + expf(-gz));
            float n = tanhf(gin + r * ghn);
            float hn = (1.f - z) * n + z * hreg;
            hreg = hn;
            hs[(size_t)s * DOUTD + j] = hn;                      // plain store for attn
            unsigned long long pay = ((unsigned long long)(unsigned)(s + 1) << 32) |
                                     (unsigned long long)__float_as_uint(hn);
            __hip_atomic_store(&hcomm[(size_t)s * DOUTD + j], pay,
                               __ATOMIC_RELAXED, __HIP_MEMORY_SCOPE_AGENT);
            hprev[j] = hn;     // self-publish own chunk (post-B; read post-A(s+1))
            if (s + 1 < TT) {  // prefetch next step's gi
                const float* gn = gi + (size_t)(s + 1) * G3;
                gir = gn[j]; giz = gn[DOUTD + j]; gin = gn[2 * DOUTD + j];
            }
        }
        // no drain, no flag: payloads are self-validating (tag == s+1)
    }
}

// ---------------- attention epilogue ----------------
__global__ void attn_kernel(const float* __restrict__ hs, const float* __restrict__ q,
                            const float* __restrict__ log_lam, float* __restrict__ out) {
    int tid = threadIdx.x;   // 512
    int wave = tid >> 6, lane = tid & 63;
    __shared__ float sc[TT];
    __shared__ float at[TT];
    __shared__ float red[8];
    __shared__ float red2[8];
    __shared__ float denom_s, mx_s;

    const float qscale = 0.04419417382415921757f;  // 1/sqrt(512)
    for (int r = wave; r < TT; r += 8) {
        float acc = 0.f;
        #pragma unroll
        for (int m = 0; m < 8; ++m) {
            int k = lane + 64 * m;
            acc = fmaf(hs[(size_t)r * DOUTD + k], q[k], acc);
        }
        for (int o = 32; o; o >>= 1) acc += __shfl_down(acc, o, 64);
        if (lane == 0) sc[r] = acc * qscale;
    }
    __syncthreads();
    float lam = fmaxf(expf(log_lam[0]), 1e-4f);
    float s_i = sc[tid] - lam * (float)(TT - 1 - tid);

    float mval = s_i;
    for (int o = 32; o; o >>= 1) mval = fmaxf(mval, __shfl_down(mval, o, 64));
    if (lane == 0) red[wave] = mval;
    __syncthreads();
    if (tid == 0) {
        float mm = red[0];
        for (int i = 1; i < 8; ++i) mm = fmaxf(mm, red[i]);
        mx_s = mm;
    }
    __syncthreads();
    float e = expf(s_i - mx_s);
    float ssum = e;
    for (int o = 32; o; o >>= 1) ssum += __shfl_down(ssum, o, 64);
    if (lane == 0) red2[wave] = ssum;
    __syncthreads();
    if (tid == 0) {
        float dsum = 0.f;
        for (int i = 0; i < 8; ++i) dsum += red2[i];
        denom_s = dsum;
    }
    __syncthreads();
    float attn = e / denom_s;
    out[DOUTD + tid] = attn;     // output 1: attn (T,)
    at[tid] = attn;
    __syncthreads();
    // summary[d]: coalesced across d for each row i
    float acc = 0.f;
    for (int i = 0; i < TT; ++i) acc = fmaf(at[i], hs[(size_t)i * DOUTD + tid], acc);
    out[tid] = acc;              // output 0: summary (1, 512)
}

extern "C" void kernel_launch(void* const* d_in, const int* in_sizes, int n_in,
                              void* d_out, int out_size, void* d_ws, size_t ws_size,
                              hipStream_t stream) {
    const int*   idx    = (const int*)d_in[0];
    const float* timef  = (const float*)d_in[1];
    const float* emb    = (const float*)d_in[2];
    const float* latlon = (const float*)d_in[3];
    const float* lnw    = (const float*)d_in[4];
    const float* lnb    = (const float*)d_in[5];
    const float* w1     = (const float*)d_in[6];
    const float* b1     = (const float*)d_in[7];
    const float* w2     = (const float*)d_in[8];
    const float* b2     = (const float*)d_in[9];
    const float* wih    = (const float*)d_in[10];  // (1536, 256)
    const float* whh    = (const float*)d_in[11];  // (1536, 512)
    const float* bih    = (const float*)d_in[12];  // (1536,)
    const float* bhh    = (const float*)d_in[13];  // (1536,)
    const float* q      = (const float*)d_in[14];
    const float* loglam = (const float*)d_in[15];
    float* out = (float*)d_out;

    unsigned long long* hcomm = (unsigned long long*)d_ws;            // 512*512 payloads (2 MB)
    float* feat = (float*)(hcomm + (size_t)TT * DOUTD);               // 2048
    float* xn   = feat + 2048;                                        // 512*260 = 133120
    float* h1   = xn + TT * DIN;                                      // 512*356 = 182272
    float* x2   = h1 + TT * DHID;                                     // 512*256 = 131072
    float* gi   = x2 + TT * DPOI;                                     // 512*1536 = 786432
    float* hs   = gi + (size_t)TT * G3;                               // 512*512 = 262144

    feat_kernel<<<1, TT, 0, stream>>>(idx, timef, latlon, feat);
    ln_kernel<<<TT, 256, 0, stream>>>(idx, emb, feat, lnw, lnb, xn);
    mlp1_kernel<<<TT, 384, 0, stream>>>(xn, w1, b1, h1);
    mlp2_kernel<<<TT, 256, 0, stream>>>(h1, w2, b2, x2);
    gi_kernel<<<TT, 256, 0, stream>>>(x2, wih, bih, gi);

    // zero all hcomm step-tags (payloads self-validate via tag == step+1)
    int n16 = (int)(((size_t)TT * DOUTD * 8) / 16);                   // 131072 uint4
    zero_kernel<<<256, 512, 0, stream>>>((uint4*)hcomm, n16);

    void* gru_args[] = { (void*)&gi, (void*)&whh, (void*)&bhh, (void*)&hs, (void*)&hcomm };
    hipLaunchCooperativeKernel((void*)gru_tag_kernel, dim3(GB), dim3(1024),
                               gru_args, 0, stream);

    attn_kernel<<<1, TT, 0, stream>>>(hs, q, loglam, out);
}

// Round 3
// 1885.395 us; speedup vs baseline: 306.6947x; 1.0124x over previous
//
#include <hip/hip_runtime.h>
#include <hip/hip_cooperative_groups.h>
#include <math.h>

namespace cg = cooperative_groups;

#define TT 512
#define DPOI 256
#define DIN 260
#define DHID 356
#define DOUTD 512
#define G3 1536

// GRU partition: 32 worker blocks x 1024 threads, 16 hidden units per block.
// Cross-block comm: agent-scope relaxed atomics on 8B self-validating payloads
// {u32 tag | bf16 h0 | bf16 h1} -> 256 units = 32 cache lines per step, ONE
// line per producer. W_hh rows live in per-lane f32 REGISTERS (each lane only
// ever needs 48 B of W) -> no LDS weight array, no per-step weight ds_reads.
#define GB 32
#define HU (DOUTD / GB)      // 16 hidden units per block
#define NR (3 * HU)          // 48 w_hh rows per block
#define NU 256               // 8B comm units per step (2 h values each)

// ---------------- feature kernel ----------------
__global__ void feat_kernel(const int* __restrict__ idx, const float* __restrict__ timef,
                            const float* __restrict__ latlon, float* __restrict__ feat) {
    int i = threadIdx.x;
    if (i >= TT) return;
    float t = fminf(fmaxf(timef[i], 0.f), 1.f);
    const float TWO_PI = 6.28318530717958647692f;
    float s = sinf(TWO_PI * t);
    float c = cosf(TWO_PI * t);
    float dt_h = 0.f, dd = 0.f;
    if (i > 0) {
        float tp = fminf(fmaxf(timef[i - 1], 0.f), 1.f);
        float d = t - tp;
        d = d - floorf(d);          // jnp.mod(x, 1.0)
        dt_h = d * 24.f;
        int i0 = idx[i - 1], i1 = idx[i];
        float la0 = latlon[2 * (size_t)i0], lo0 = latlon[2 * (size_t)i0 + 1];
        float la1 = latlon[2 * (size_t)i1], lo1 = latlon[2 * (size_t)i1 + 1];
        const float D2R = 0.01745329251994329577f;
        float lat1 = fminf(fmaxf(la0, -90.f), 90.f) * D2R;
        float lon1 = fminf(fmaxf(lo0, -180.f), 180.f) * D2R;
        float lat2 = fminf(fmaxf(la1, -90.f), 90.f) * D2R;
        float lon2 = fminf(fmaxf(lo1, -180.f), 180.f) * D2R;
        float dlat = (lat2 - lat1) * 0.5f, dlon = (lon2 - lon1) * 0.5f;
        float sdlat = sinf(dlat), sdlon = sinf(dlon);
        float a = sdlat * sdlat +
                  fminf(fmaxf(cosf(lat1), -1.f), 1.f) * fminf(fmaxf(cosf(lat2), -1.f), 1.f) * sdlon * sdlon;
        float aa = fminf(fmaxf(a, 0.f), 1.f);
        float bb = fminf(fmaxf(1.f - a, 1e-12f), 1.f);
        float cc = 2.f * atan2f(sqrtf(aa), sqrtf(bb));
        dd = 6371.0088f * cc;
    }
    feat[4 * i + 0] = s;
    feat[4 * i + 1] = c;
    feat[4 * i + 2] = log1pf(dt_h);
    feat[4 * i + 3] = log1pf(dd);
}

// ---------------- gather + layernorm ----------------
__global__ void ln_kernel(const int* __restrict__ idx, const float* __restrict__ emb,
                          const float* __restrict__ feat, const float* __restrict__ lnw,
                          const float* __restrict__ lnb, float* __restrict__ xn) {
    int t = blockIdx.x;
    int tid = threadIdx.x;           // 256 threads
    int wave = tid >> 6, lane = tid & 63;
    const float* row = emb + (size_t)idx[t] * DPOI;
    float v0 = row[tid];
    float v1 = (tid < 4) ? feat[4 * t + tid] : 0.f;

    __shared__ float red[4];
    __shared__ float mu_s, rs_s;

    float s = v0 + v1;
    for (int o = 32; o; o >>= 1) s += __shfl_down(s, o, 64);
    if (lane == 0) red[wave] = s;
    __syncthreads();
    if (tid == 0) mu_s = (red[0] + red[1] + red[2] + red[3]) * (1.f / 260.f);
    __syncthreads();
    float mu = mu_s;
    float d0 = v0 - mu;
    float d1 = (tid < 4) ? (v1 - mu) : 0.f;
    float sq = d0 * d0 + d1 * d1;
    for (int o = 32; o; o >>= 1) sq += __shfl_down(sq, o, 64);
    __syncthreads();
    if (lane == 0) red[wave] = sq;
    __syncthreads();
    if (tid == 0) {
        float var = (red[0] + red[1] + red[2] + red[3]) * (1.f / 260.f);
        rs_s = rsqrtf(var + 1e-5f);
    }
    __syncthreads();
    float rs = rs_s;
    xn[t * DIN + tid] = d0 * rs * lnw[tid] + lnb[tid];
    if (tid < 4)
        xn[t * DIN + 256 + tid] = d1 * rs * lnw[256 + tid] + lnb[256 + tid];
}

// ---------------- x @ w1 + b1, gelu ----------------
__global__ void mlp1_kernel(const float* __restrict__ xn, const float* __restrict__ w1,
                            const float* __restrict__ b1, float* __restrict__ h1) {
    int t = blockIdx.x, j = threadIdx.x;   // 384 threads
    __shared__ float xl[DIN];
    for (int k = threadIdx.x; k < DIN; k += blockDim.x) xl[k] = xn[t * DIN + k];
    __syncthreads();
    if (j < DHID) {
        float acc = b1[j];
        #pragma unroll 4
        for (int k = 0; k < DIN; ++k) acc = fmaf(xl[k], w1[k * DHID + j], acc);
        float g = 0.5f * acc * (1.f + erff(acc * 0.70710678118654752440f));
        h1[t * DHID + j] = g;
    }
}

// ---------------- h1 @ w2 + b2 ----------------
__global__ void mlp2_kernel(const float* __restrict__ h1, const float* __restrict__ w2,
                            const float* __restrict__ b2, float* __restrict__ x2) {
    int t = blockIdx.x, j = threadIdx.x;   // 256 threads
    __shared__ float xl[DHID];
    for (int k = threadIdx.x; k < DHID; k += blockDim.x) xl[k] = h1[t * DHID + k];
    __syncthreads();
    float acc = b2[j];
    #pragma unroll 4
    for (int k = 0; k < DHID; ++k) acc = fmaf(xl[k], w2[k * DPOI + j], acc);
    x2[t * DPOI + j] = acc;
}

// ---------------- gi = x2 @ w_ih.T + b_ih ----------------
__global__ void gi_kernel(const float* __restrict__ x2, const float* __restrict__ wih,
                          const float* __restrict__ bih, float* __restrict__ gi) {
    int t = blockIdx.x;
    int tid = threadIdx.x;   // 256
    int wave = tid >> 6, lane = tid & 63;
    float4 xv = ((const float4*)(x2 + (size_t)t * DPOI))[lane];
    for (int r = wave; r < G3; r += 4) {
        float4 wv = ((const float4*)(wih + (size_t)r * DPOI))[lane];
        float s = xv.x * wv.x + xv.y * wv.y + xv.z * wv.z + xv.w * wv.w;
        for (int o = 32; o; o >>= 1) s += __shfl_down(s, o, 64);
        if (lane == 0) gi[(size_t)t * G3 + r] = s + bih[r];
    }
}

// ---------------- zero hcomm tags ----------------
__global__ void zero_kernel(uint4* __restrict__ p, int n16) {
    int i = blockIdx.x * blockDim.x + threadIdx.x;
    int stride = gridDim.x * blockDim.x;
    uint4 z; z.x = 0u; z.y = 0u; z.z = 0u; z.w = 0u;
    for (; i < n16; i += stride) p[i] = z;
}

// ---------------- GRU scan: packed bf16-pair tagged payloads ----------------
__global__ __launch_bounds__(1024)
void gru_tag_kernel(const float* __restrict__ gi, const float* __restrict__ whh,
                    const float* __restrict__ bhh, float* __restrict__ hs,
                    unsigned long long* __restrict__ hcomm) {
    __shared__ float hprev[DOUTD];            // 2 KB
    __shared__ float gsum[NR];

    int b = blockIdx.x;        // 0..31
    int tid = threadIdx.x;     // 0..1023
    int wave = tid >> 6, lane = tid & 63;
    int jbase = b * HU;

    // --- W_hh fragments -> registers (f32). Lane `lane` of wave `wave` owns
    //     rows rr = 3*wave..3*wave+2, k = 4*lane..4*lane+3 and 256+4*lane..+3.
    float4 wa0, wb0, wa1, wb1, wa2, wb2;
    float bl0, bl1, bl2;
    {
        int rr = wave * 3;
        int g0 = (rr + 0) >> 4, j0 = (rr + 0) & 15;
        int g1 = (rr + 1) >> 4, j1 = (rr + 1) & 15;
        int g2 = (rr + 2) >> 4, j2 = (rr + 2) & 15;
        const float4* r0 = (const float4*)(whh + (size_t)(g0 * DOUTD + jbase + j0) * DOUTD);
        const float4* r1 = (const float4*)(whh + (size_t)(g1 * DOUTD + jbase + j1) * DOUTD);
        const float4* r2 = (const float4*)(whh + (size_t)(g2 * DOUTD + jbase + j2) * DOUTD);
        wa0 = r0[lane]; wb0 = r0[64 + lane];
        wa1 = r1[lane]; wb1 = r1[64 + lane];
        wa2 = r2[lane]; wb2 = r2[64 + lane];
        bl0 = bhh[g0 * DOUTD + jbase + j0];
        bl1 = bhh[g1 * DOUTD + jbase + j1];
        bl2 = bhh[g2 * DOUTD + jbase + j2];
    }
    if (tid < DOUTD) hprev[tid] = 0.f;
    __syncthreads();

    const float4* hp4 = (const float4*)hprev;
    long budget = 2L * 1000 * 1000;   // lifetime spin budget: deadlock -> numeric fail

    // gi prefetch registers (gate lanes only), one step ahead; own h in register.
    float gir = 0.f, giz = 0.f, gin = 0.f, hreg = 0.f;
    if (tid < HU) {
        int j = jbase + tid;
        gir = gi[j];
        giz = gi[DOUTD + j];
        gin = gi[2 * DOUTD + j];
    }

    for (int s = 0; s < TT; ++s) {
        if (s > 0) {
            // lanes 0..15 of wave w poll unit u = 16w + lane (256 units total);
            // unit u carries h[2u], h[2u+1] as bf16 + u32 step tag. Own block's
            // units are self-published through LDS by the gate lanes.
            if (lane < 16) {
                int u = (wave << 4) + lane;
                bool own = (u >> 3) == b;
                const unsigned long long* ap = hcomm + (size_t)(s - 1) * NU + u;
                unsigned long long p = 0;
                bool ok = own;
                while (!__all(ok)) {
                    if (!ok) {
                        p = __hip_atomic_load(ap, __ATOMIC_RELAXED,
                                              __HIP_MEMORY_SCOPE_AGENT);
                        ok = ((unsigned)p == (unsigned)s);
                    }
                    if (--budget < 0) break;
                }
                if (!own) {
                    unsigned hi = (unsigned)(p >> 32);
                    float2 hv;
                    hv.x = __uint_as_float(hi & 0xffff0000u);
                    hv.y = __uint_as_float(hi << 16);
                    *(float2*)&hprev[2 * u] = hv;
                }
            }
            __syncthreads();   // barrier A: full h_{s-1} in hprev
        }

        // matvec: 48 rows over 16 waves -> 3 rows/wave, weights in registers.
        float4 ha = hp4[lane];
        float4 hb = hp4[64 + lane];
        float a0, a1, a2;
        a0 = wa0.x * ha.x; a1 = wa1.x * ha.x; a2 = wa2.x * ha.x;
        a0 = fmaf(wa0.y, ha.y, a0); a1 = fmaf(wa1.y, ha.y, a1); a2 = fmaf(wa2.y, ha.y, a2);
        a0 = fmaf(wa0.z, ha.z, a0); a1 = fmaf(wa1.z, ha.z, a1); a2 = fmaf(wa2.z, ha.z, a2);
        a0 = fmaf(wa0.w, ha.w, a0); a1 = fmaf(wa1.w, ha.w, a1); a2 = fmaf(wa2.w, ha.w, a2);
        a0 = fmaf(wb0.x, hb.x, a0); a1 = fmaf(wb1.x, hb.x, a1); a2 = fmaf(wb2.x, hb.x, a2);
        a0 = fmaf(wb0.y, hb.y, a0); a1 = fmaf(wb1.y, hb.y, a1); a2 = fmaf(wb2.y, hb.y, a2);
        a0 = fmaf(wb0.z, hb.z, a0); a1 = fmaf(wb1.z, hb.z, a1); a2 = fmaf(wb2.z, hb.z, a2);
        a0 = fmaf(wb0.w, hb.w, a0); a1 = fmaf(wb1.w, hb.w, a1); a2 = fmaf(wb2.w, hb.w, a2);
        for (int o = 32; o; o >>= 1) {
            a0 += __shfl_down(a0, o, 64);
            a1 += __shfl_down(a1, o, 64);
            a2 += __shfl_down(a2, o, 64);
        }
        if (lane == 0) {
            int rr = wave * 3;
            gsum[rr]     = a0 + bl0;
            gsum[rr + 1] = a1 + bl1;
            gsum[rr + 2] = a2 + bl2;
        }
        __syncthreads();       // barrier B: gsum complete; all hprev reads done

        if (tid < HU) {        // wave 0, lanes 0..15: gates + publish
            int j = jbase + tid;
            float gr  = gir + gsum[tid];
            float gz  = giz + gsum[HU + tid];
            float ghn = gsum[2 * HU + tid];
            float r = 1.f / (1.f + expf(-gr));
            float z = 1.f / (1.f + expf(-gz));
            float n = tanhf(gin + r * ghn);
            float hn = (1.f - z) * n + z * hreg;
            hreg = hn;
            // pack pairs: lane i<8 publishes {h[2i], h[2i+1]} of this block
            unsigned ub = __float_as_uint(hn);
            ub += 0x7fffu + ((ub >> 16) & 1u);        // RNE f32 -> bf16
            unsigned bh = ub >> 16;
            unsigned p0 = (unsigned)__shfl((int)bh, (tid & 7) * 2, 64);
            unsigned p1 = (unsigned)__shfl((int)bh, (tid & 7) * 2 + 1, 64);
            if (tid < 8) {
                unsigned long long pay = ((unsigned long long)((p0 << 16) | p1) << 32) |
                                         (unsigned)(s + 1);
                __hip_atomic_store(&hcomm[(size_t)s * NU + b * 8 + tid], pay,
                                   __ATOMIC_RELAXED, __HIP_MEMORY_SCOPE_AGENT);
            }
            hs[(size_t)s * DOUTD + j] = hn;   // full-f32 copy for the attn epilogue
            hprev[j] = hn;                    // self-publish own chunk
            if (s + 1 < TT) {                 // prefetch next step's gi
                const float* gn = gi + (size_t)(s + 1) * G3;
                gir = gn[j]; giz = gn[DOUTD + j]; gin = gn[2 * DOUTD + j];
            }
        }
        // no drain, no flag: payloads self-validate (tag == s+1)
    }
}

// ---------------- attention epilogue ----------------
__global__ void attn_kernel(const float* __restrict__ hs, const float* __restrict__ q,
                            const float* __restrict__ log_lam, float* __restrict__ out) {
    int tid = threadIdx.x;   // 512
    int wave = tid >> 6, lane = tid & 63;
    __shared__ float sc[TT];
    __shared__ float at[TT];
    __shared__ float red[8];
    __shared__ float red2[8];
    __shared__ float denom_s, mx_s;

    const float qscale = 0.04419417382415921757f;  // 1/sqrt(512)
    for (int r = wave; r < TT; r += 8) {
        float acc = 0.f;
        #pragma unroll
        for (int m = 0; m < 8; ++m) {
            int k = lane + 64 * m;
            acc = fmaf(hs[(size_t)r * DOUTD + k], q[k], acc);
        }
        for (int o = 32; o; o >>= 1) acc += __shfl_down(acc, o, 64);
        if (lane == 0) sc[r] = acc * qscale;
    }
    __syncthreads();
    float lam = fmaxf(expf(log_lam[0]), 1e-4f);
    float s_i = sc[tid] - lam * (float)(TT - 1 - tid);

    float mval = s_i;
    for (int o = 32; o; o >>= 1) mval = fmaxf(mval, __shfl_down(mval, o, 64));
    if (lane == 0) red[wave] = mval;
    __syncthreads();
    if (tid == 0) {
        float mm = red[0];
        for (int i = 1; i < 8; ++i) mm = fmaxf(mm, red[i]);
        mx_s = mm;
    }
    __syncthreads();
    float e = expf(s_i - mx_s);
    float ssum = e;
    for (int o = 32; o; o >>= 1) ssum += __shfl_down(ssum, o, 64);
    if (lane == 0) red2[wave] = ssum;
    __syncthreads();
    if (tid == 0) {
        float dsum = 0.f;
        for (int i = 0; i < 8; ++i) dsum += red2[i];
        denom_s = dsum;
    }
    __syncthreads();
    float attn = e / denom_s;
    out[DOUTD + tid] = attn;     // output 1: attn (T,)
    at[tid] = attn;
    __syncthreads();
    // summary[d]: coalesced across d for each row i
    float acc = 0.f;
    for (int i = 0; i < TT; ++i) acc = fmaf(at[i], hs[(size_t)i * DOUTD + tid], acc);
    out[tid] = acc;              // output 0: summary (1, 512)
}

extern "C" void kernel_launch(void* const* d_in, const int* in_sizes, int n_in,
                              void* d_out, int out_size, void* d_ws, size_t ws_size,
                              hipStream_t stream) {
    const int*   idx    = (const int*)d_in[0];
    const float* timef  = (const float*)d_in[1];
    const float* emb    = (const float*)d_in[2];
    const float* latlon = (const float*)d_in[3];
    const float* lnw    = (const float*)d_in[4];
    const float* lnb    = (const float*)d_in[5];
    const float* w1     = (const float*)d_in[6];
    const float* b1     = (const float*)d_in[7];
    const float* w2     = (const float*)d_in[8];
    const float* b2     = (const float*)d_in[9];
    const float* wih    = (const float*)d_in[10];  // (1536, 256)
    const float* whh    = (const float*)d_in[11];  // (1536, 512)
    const float* bih    = (const float*)d_in[12];  // (1536,)
    const float* bhh    = (const float*)d_in[13];  // (1536,)
    const float* q      = (const float*)d_in[14];
    const float* loglam = (const float*)d_in[15];
    float* out = (float*)d_out;

    unsigned long long* hcomm = (unsigned long long*)d_ws;            // 512*256 units (1 MB)
    float* feat = (float*)(hcomm + (size_t)TT * NU);                  // 2048
    float* xn   = feat + 2048;                                        // 512*260 = 133120
    float* h1   = xn + TT * DIN;                                      // 512*356 = 182272
    float* x2   = h1 + TT * DHID;                                     // 512*256 = 131072
    float* gi   = x2 + TT * DPOI;                                     // 512*1536 = 786432
    float* hs   = gi + (size_t)TT * G3;                               // 512*512 = 262144

    feat_kernel<<<1, TT, 0, stream>>>(idx, timef, latlon, feat);
    ln_kernel<<<TT, 256, 0, stream>>>(idx, emb, feat, lnw, lnb, xn);
    mlp1_kernel<<<TT, 384, 0, stream>>>(xn, w1, b1, h1);
    mlp2_kernel<<<TT, 256, 0, stream>>>(h1, w2, b2, x2);
    gi_kernel<<<TT, 256, 0, stream>>>(x2, wih, bih, gi);

    // zero all hcomm step-tags (payloads self-validate via tag == step+1)
    int n16 = (int)(((size_t)TT * NU * 8) / 16);                      // 65536 uint4
    zero_kernel<<<256, 512, 0, stream>>>((uint4*)hcomm, n16);

    void* gru_args[] = { (void*)&gi, (void*)&whh, (void*)&bhh, (void*)&hs, (void*)&hcomm };
    hipLaunchCooperativeKernel((void*)gru_tag_kernel, dim3(GB), dim3(1024),
                               gru_args, 0, stream);

    attn_kernel<<<1, TT, 0, stream>>>(hs, q, loglam, out);
}

// Round 4
// 1848.608 us; speedup vs baseline: 312.7979x; 1.0199x over previous
//
#include <hip/hip_runtime.h>
#include <hip/hip_cooperative_groups.h>
#include <math.h>

namespace cg = cooperative_groups;

#define TT 512
#define DPOI 256
#define DIN 260
#define DHID 356
#define DOUTD 512
#define G3 1536

// GRU partition: 8 worker blocks x 1024 threads, 64 hidden units per block.
// Cross-block comm: agent-scope relaxed atomics on 8B self-validating payloads
// {bf16 h (as f32-hi bits) | u32 step-tag}. 512 payloads = 64 lines per step,
// 8 lines per producer, stored coalesced by one wave. W_hh (192 rows) lives in
// per-lane f32 registers. Gates run on a full 64-lane wave. Pollers are waves
// 4..11 so the gate wave goes straight to the barrier. Attention epilogue is
// fused behind a grid sync.
#define GB 8
#define HU (DOUTD / GB)      // 64 hidden units per block
#define NRR (3 * HU)         // 192 w_hh rows per block
#define NPAY DOUTD           // 512 payload units per step

// ---------------- gather + layernorm (features inlined) ----------------
__global__ void ln_kernel(const int* __restrict__ idx, const float* __restrict__ timef,
                          const float* __restrict__ latlon, const float* __restrict__ emb,
                          const float* __restrict__ lnw, const float* __restrict__ lnb,
                          float* __restrict__ xn) {
    int t = blockIdx.x;
    int tid = threadIdx.x;           // 256 threads
    int wave = tid >> 6, lane = tid & 63;

    // --- inline features (computed redundantly per thread; gathers broadcast) ---
    float tv = fminf(fmaxf(timef[t], 0.f), 1.f);
    const float TWO_PI = 6.28318530717958647692f;
    float f0 = sinf(TWO_PI * tv);
    float f1 = cosf(TWO_PI * tv);
    float f2 = 0.f, f3 = 0.f;
    if (t > 0) {
        float tp = fminf(fmaxf(timef[t - 1], 0.f), 1.f);
        float d = tv - tp;
        d = d - floorf(d);          // jnp.mod(x, 1.0)
        f2 = log1pf(d * 24.f);
        int i0 = idx[t - 1], i1 = idx[t];
        float la0 = latlon[2 * (size_t)i0], lo0 = latlon[2 * (size_t)i0 + 1];
        float la1 = latlon[2 * (size_t)i1], lo1 = latlon[2 * (size_t)i1 + 1];
        const float D2R = 0.01745329251994329577f;
        float lat1 = fminf(fmaxf(la0, -90.f), 90.f) * D2R;
        float lon1 = fminf(fmaxf(lo0, -180.f), 180.f) * D2R;
        float lat2 = fminf(fmaxf(la1, -90.f), 90.f) * D2R;
        float lon2 = fminf(fmaxf(lo1, -180.f), 180.f) * D2R;
        float dlat = (lat2 - lat1) * 0.5f, dlon = (lon2 - lon1) * 0.5f;
        float sdlat = sinf(dlat), sdlon = sinf(dlon);
        float a = sdlat * sdlat +
                  fminf(fmaxf(cosf(lat1), -1.f), 1.f) * fminf(fmaxf(cosf(lat2), -1.f), 1.f) * sdlon * sdlon;
        float aa = fminf(fmaxf(a, 0.f), 1.f);
        float bb = fminf(fmaxf(1.f - a, 1e-12f), 1.f);
        float cc = 2.f * atan2f(sqrtf(aa), sqrtf(bb));
        f3 = log1pf(6371.0088f * cc);
    }
    float fv = (tid == 0) ? f0 : (tid == 1) ? f1 : (tid == 2) ? f2 : f3;

    const float* row = emb + (size_t)idx[t] * DPOI;
    float v0 = row[tid];
    float v1 = (tid < 4) ? fv : 0.f;

    __shared__ float red[4];
    __shared__ float mu_s, rs_s;

    float s = v0 + v1;
    for (int o = 32; o; o >>= 1) s += __shfl_down(s, o, 64);
    if (lane == 0) red[wave] = s;
    __syncthreads();
    if (tid == 0) mu_s = (red[0] + red[1] + red[2] + red[3]) * (1.f / 260.f);
    __syncthreads();
    float mu = mu_s;
    float d0 = v0 - mu;
    float d1 = (tid < 4) ? (v1 - mu) : 0.f;
    float sq = d0 * d0 + d1 * d1;
    for (int o = 32; o; o >>= 1) sq += __shfl_down(sq, o, 64);
    __syncthreads();
    if (lane == 0) red[wave] = sq;
    __syncthreads();
    if (tid == 0) {
        float var = (red[0] + red[1] + red[2] + red[3]) * (1.f / 260.f);
        rs_s = rsqrtf(var + 1e-5f);
    }
    __syncthreads();
    float rs = rs_s;
    xn[t * DIN + tid] = d0 * rs * lnw[tid] + lnb[tid];
    if (tid < 4)
        xn[t * DIN + 256 + tid] = d1 * rs * lnw[256 + tid] + lnb[256 + tid];
}

// ---------------- x @ w1 + b1, gelu ----------------
__global__ void mlp1_kernel(const float* __restrict__ xn, const float* __restrict__ w1,
                            const float* __restrict__ b1, float* __restrict__ h1) {
    int t = blockIdx.x, j = threadIdx.x;   // 384 threads
    __shared__ float xl[DIN];
    for (int k = threadIdx.x; k < DIN; k += blockDim.x) xl[k] = xn[t * DIN + k];
    __syncthreads();
    if (j < DHID) {
        float acc = b1[j];
        #pragma unroll 4
        for (int k = 0; k < DIN; ++k) acc = fmaf(xl[k], w1[k * DHID + j], acc);
        float g = 0.5f * acc * (1.f + erff(acc * 0.70710678118654752440f));
        h1[t * DHID + j] = g;
    }
}

// ---------------- h1 @ w2 + b2 ----------------
__global__ void mlp2_kernel(const float* __restrict__ h1, const float* __restrict__ w2,
                            const float* __restrict__ b2, float* __restrict__ x2) {
    int t = blockIdx.x, j = threadIdx.x;   // 256 threads
    __shared__ float xl[DHID];
    for (int k = threadIdx.x; k < DHID; k += blockDim.x) xl[k] = h1[t * DHID + k];
    __syncthreads();
    float acc = b2[j];
    #pragma unroll 4
    for (int k = 0; k < DHID; ++k) acc = fmaf(xl[k], w2[k * DPOI + j], acc);
    x2[t * DPOI + j] = acc;
}

// ---------------- gi = x2 @ w_ih.T + b_ih (+ hcomm zeroing folded in) ----------------
__global__ void gi_kernel(const float* __restrict__ x2, const float* __restrict__ wih,
                          const float* __restrict__ bih, float* __restrict__ gi,
                          uint4* __restrict__ hcz) {
    int t = blockIdx.x;
    int tid = threadIdx.x;   // 256
    int wave = tid >> 6, lane = tid & 63;
    // zero this block's slice of hcomm step-tags (2 MB total / 512 blocks)
    uint4 z; z.x = 0u; z.y = 0u; z.z = 0u; z.w = 0u;
    hcz[(size_t)t * 256 + tid] = z;
    float4 xv = ((const float4*)(x2 + (size_t)t * DPOI))[lane];
    for (int r = wave; r < G3; r += 4) {
        float4 wv = ((const float4*)(wih + (size_t)r * DPOI))[lane];
        float s = xv.x * wv.x + xv.y * wv.y + xv.z * wv.z + xv.w * wv.w;
        for (int o = 32; o; o >>= 1) s += __shfl_down(s, o, 64);
        if (lane == 0) gi[(size_t)t * G3 + r] = s + bih[r];
    }
}

// ---------------- fused GRU scan + attention epilogue ----------------
__global__ __launch_bounds__(1024)
void gru_fused_kernel(const float* __restrict__ gi, const float* __restrict__ whh,
                      const float* __restrict__ bhh, float* __restrict__ hs,
                      unsigned long long* __restrict__ hcomm,
                      const float* __restrict__ q, const float* __restrict__ log_lam,
                      float* __restrict__ out) {
    __shared__ float hprev[DOUTD];     // 2 KB
    __shared__ float gsum[NRR];        // 768 B
    __shared__ float sc[TT];           // attn scratch (used after grid sync)
    __shared__ float at[TT];
    __shared__ float red[8];
    __shared__ float red2[8];
    __shared__ float denom_s, mx_s;

    int b = blockIdx.x;        // 0..7
    int tid = threadIdx.x;     // 0..1023
    int wave = tid >> 6, lane = tid & 63;
    int jbase = b * HU;
    int g4 = lane >> 4, l4 = lane & 15;
    int rr0 = wave * 12 + g4 * 3;      // this lane-group's 3 rows (rr0..rr0+2)

    // --- W_hh fragments -> f32 registers. Lane covers k = m*64 + l4*4 + {0..3}
    //     (strided chunks: LDS float4 reads land ~2 addrs per bank group). ---
    float4 wf0[8], wf1[8], wf2[8];
    float bl0, bl1, bl2;
    {
        int r0 = rr0, r1 = rr0 + 1, r2 = rr0 + 2;
        const float4* p0 = (const float4*)(whh + (size_t)((r0 >> 6) * DOUTD + jbase + (r0 & 63)) * DOUTD);
        const float4* p1 = (const float4*)(whh + (size_t)((r1 >> 6) * DOUTD + jbase + (r1 & 63)) * DOUTD);
        const float4* p2 = (const float4*)(whh + (size_t)((r2 >> 6) * DOUTD + jbase + (r2 & 63)) * DOUTD);
        #pragma unroll
        for (int m = 0; m < 8; ++m) {
            wf0[m] = p0[m * 16 + l4];
            wf1[m] = p1[m * 16 + l4];
            wf2[m] = p2[m * 16 + l4];
        }
        bl0 = bhh[(r0 >> 6) * DOUTD + jbase + (r0 & 63)];
        bl1 = bhh[(r1 >> 6) * DOUTD + jbase + (r1 & 63)];
        bl2 = bhh[(r2 >> 6) * DOUTD + jbase + (r2 & 63)];
    }
    if (tid < DOUTD) hprev[tid] = 0.f;
    __syncthreads();

    const float4* hp4 = (const float4*)hprev;
    long budget = 2L * 1000 * 1000;   // lifetime spin budget: deadlock -> numeric fail
    float dj = (float)tid * 1e-6f;    // clock-keeper accumulator (kept live below)

    // gi prefetch registers (gate wave only), one step ahead; own h in register.
    float gir = 0.f, giz = 0.f, gin = 0.f, hreg = 0.f;
    if (tid < HU) {
        int j = jbase + tid;
        gir = gi[j];
        giz = gi[DOUTD + j];
        gin = gi[2 * DOUTD + j];
    }

    for (int s = 0; s < TT; ++s) {
        if (s > 0) {
            // waves 4..11 poll unit u = tid-256 (512 units); wave 0 (the gate
            // wave) skips straight to the barrier. Own units were written to
            // hprev by the gate phase.
            if (tid >= 256 && tid < 768) {
                int u = tid - 256;
                bool own = (u >> 6) == b;
                const unsigned long long* ap = hcomm + (size_t)(s - 1) * NPAY + u;
                unsigned long long p = 0;
                bool ok = own;
                unsigned tagw = (unsigned)s;
                while (!__all(ok)) {
                    if (!ok) {
                        p = __hip_atomic_load(ap, __ATOMIC_RELAXED,
                                              __HIP_MEMORY_SCOPE_AGENT);
                        ok = ((unsigned)p == tagw);
                    }
                    // clock-keeper: keep the VALU busy while spinning (DVFS)
                    float x = dj;
                    #pragma unroll
                    for (int zz = 0; zz < 8; ++zz) x = fmaf(x, 1.0000001f, 1e-7f);
                    dj = x;
                    if (--budget < 0) break;
                }
                if (!own) hprev[u] = __uint_as_float((unsigned)(p >> 32));
            }
            __syncthreads();   // barrier A: full h_{s-1} in hprev
        }

        // matvec: 192 rows; wave w, lane-group g4 -> rows rr0..rr0+2, 16-lane
        // k-split, 96 FMAs/lane, 4-stage xor-reduce within the 16-lane group.
        float a0 = 0.f, a1 = 0.f, a2 = 0.f;
        #pragma unroll
        for (int m = 0; m < 8; ++m) {
            float4 h4 = hp4[m * 16 + l4];
            a0 = fmaf(wf0[m].x, h4.x, a0); a0 = fmaf(wf0[m].y, h4.y, a0);
            a0 = fmaf(wf0[m].z, h4.z, a0); a0 = fmaf(wf0[m].w, h4.w, a0);
            a1 = fmaf(wf1[m].x, h4.x, a1); a1 = fmaf(wf1[m].y, h4.y, a1);
            a1 = fmaf(wf1[m].z, h4.z, a1); a1 = fmaf(wf1[m].w, h4.w, a1);
            a2 = fmaf(wf2[m].x, h4.x, a2); a2 = fmaf(wf2[m].y, h4.y, a2);
            a2 = fmaf(wf2[m].z, h4.z, a2); a2 = fmaf(wf2[m].w, h4.w, a2);
        }
        #pragma unroll
        for (int o = 1; o < 16; o <<= 1) {
            a0 += __shfl_xor(a0, o, 64);
            a1 += __shfl_xor(a1, o, 64);
            a2 += __shfl_xor(a2, o, 64);
        }
        if (l4 == 0) {
            gsum[rr0]     = a0 + bl0;
            gsum[rr0 + 1] = a1 + bl1;
            gsum[rr0 + 2] = a2 + bl2;
        }
        __syncthreads();       // barrier B: gsum complete; all hprev reads done

        if (tid < HU) {        // gate wave: full 64 lanes, one unit each
            float gr  = gir + gsum[tid];
            float gz  = giz + gsum[HU + tid];
            float ghn = gsum[2 * HU + tid];
            // fast sigmoid / tanh (v_exp + v_rcp); saturates correctly at +-inf
            float r = __builtin_amdgcn_rcpf(1.f + __expf(-gr));
            float z = __builtin_amdgcn_rcpf(1.f + __expf(-gz));
            float xt = gin + r * ghn;
            float n = 1.f - 2.f * __builtin_amdgcn_rcpf(__expf(2.f * xt) + 1.f);
            float hn = (1.f - z) * n + z * hreg;
            hreg = hn;
            // publish FIRST: {bf16 h (f32-hi bits) | tag}, 64 lanes coalesced
            unsigned ub = __float_as_uint(hn);
            ub += 0x7fffu + ((ub >> 16) & 1u);        // RNE f32 -> bf16
            unsigned long long pay = ((unsigned long long)(ub & 0xffff0000u) << 32) |
                                     (unsigned)(s + 1);
            __hip_atomic_store(&hcomm[(size_t)s * NPAY + jbase + tid], pay,
                               __ATOMIC_RELAXED, __HIP_MEMORY_SCOPE_AGENT);
            int j = jbase + tid;
            hs[(size_t)s * DOUTD + j] = hn;   // full-f32 copy for the attn epilogue
            hprev[j] = hn;                    // self-publish own chunk
            if (s + 1 < TT) {                 // prefetch next step's gi
                const float* gn = gi + (size_t)(s + 1) * G3;
                gir = gn[j]; giz = gn[DOUTD + j]; gin = gn[2 * DOUTD + j];
            }
        }
        // no drain, no flag: payloads self-validate (tag == s+1)
    }

    asm volatile("" :: "v"(dj));   // keep the clock-keeper live

    // ---------------- fused attention epilogue ----------------
    cg::this_grid().sync();        // hs complete and visible
    if (b != 0) return;

    const float qscale = 0.04419417382415921757f;  // 1/sqrt(512)
    for (int r = wave; r < TT; r += 16) {
        float acc = 0.f;
        #pragma unroll
        for (int m = 0; m < 8; ++m) {
            int k = lane + 64 * m;
            acc = fmaf(hs[(size_t)r * DOUTD + k], q[k], acc);
        }
        for (int o = 32; o; o >>= 1) acc += __shfl_down(acc, o, 64);
        if (lane == 0) sc[r] = acc * qscale;
    }
    __syncthreads();
    float lam = fmaxf(expf(log_lam[0]), 1e-4f);
    float s_i = (tid < TT) ? (sc[tid] - lam * (float)(TT - 1 - tid)) : -1e30f;

    float mval = s_i;
    for (int o = 32; o; o >>= 1) mval = fmaxf(mval, __shfl_down(mval, o, 64));
    if (lane == 0 && wave < 8) red[wave] = mval;
    __syncthreads();
    if (tid == 0) {
        float mm = red[0];
        for (int i = 1; i < 8; ++i) mm = fmaxf(mm, red[i]);
        mx_s = mm;
    }
    __syncthreads();
    float e = (tid < TT) ? expf(s_i - mx_s) : 0.f;
    float ssum = e;
    for (int o = 32; o; o >>= 1) ssum += __shfl_down(ssum, o, 64);
    if (lane == 0 && wave < 8) red2[wave] = ssum;
    __syncthreads();
    if (tid == 0) {
        float dsum = 0.f;
        for (int i = 0; i < 8; ++i) dsum += red2[i];
        denom_s = dsum;
    }
    __syncthreads();
    if (tid < TT) {
        float attn = e / denom_s;
        out[DOUTD + tid] = attn;     // output 1: attn (T,)
        at[tid] = attn;
    }
    __syncthreads();
    if (tid < TT) {
        float acc = 0.f;
        for (int i = 0; i < TT; ++i) acc = fmaf(at[i], hs[(size_t)i * DOUTD + tid], acc);
        out[tid] = acc;              // output 0: summary (1, 512)
    }
}

extern "C" void kernel_launch(void* const* d_in, const int* in_sizes, int n_in,
                              void* d_out, int out_size, void* d_ws, size_t ws_size,
                              hipStream_t stream) {
    const int*   idx    = (const int*)d_in[0];
    const float* timef  = (const float*)d_in[1];
    const float* emb    = (const float*)d_in[2];
    const float* latlon = (const float*)d_in[3];
    const float* lnw    = (const float*)d_in[4];
    const float* lnb    = (const float*)d_in[5];
    const float* w1     = (const float*)d_in[6];
    const float* b1     = (const float*)d_in[7];
    const float* w2     = (const float*)d_in[8];
    const float* b2     = (const float*)d_in[9];
    const float* wih    = (const float*)d_in[10];  // (1536, 256)
    const float* whh    = (const float*)d_in[11];  // (1536, 512)
    const float* bih    = (const float*)d_in[12];  // (1536,)
    const float* bhh    = (const float*)d_in[13];  // (1536,)
    const float* q      = (const float*)d_in[14];
    const float* loglam = (const float*)d_in[15];
    float* out = (float*)d_out;

    unsigned long long* hcomm = (unsigned long long*)d_ws;            // 512*512 units (2 MB)
    float* xn   = (float*)(hcomm + (size_t)TT * NPAY);                // 512*260 = 133120
    float* h1   = xn + TT * DIN;                                      // 512*356 = 182272
    float* x2   = h1 + TT * DHID;                                     // 512*256 = 131072
    float* gi   = x2 + TT * DPOI;                                     // 512*1536 = 786432
    float* hs   = gi + (size_t)TT * G3;                               // 512*512 = 262144

    ln_kernel<<<TT, 256, 0, stream>>>(idx, timef, latlon, emb, lnw, lnb, xn);
    mlp1_kernel<<<TT, 384, 0, stream>>>(xn, w1, b1, h1);
    mlp2_kernel<<<TT, 256, 0, stream>>>(h1, w2, b2, x2);
    gi_kernel<<<TT, 256, 0, stream>>>(x2, wih, bih, gi, (uint4*)hcomm);

    void* gru_args[] = { (void*)&gi, (void*)&whh, (void*)&bhh, (void*)&hs,
                         (void*)&hcomm, (void*)&q, (void*)&loglam, (void*)&out };
    hipLaunchCooperativeKernel((void*)gru_fused_kernel, dim3(GB), dim3(1024),
                               gru_args, 0, stream);
}

// Round 5
// 1535.969 us; speedup vs baseline: 376.4663x; 1.2035x over previous
//
#include <hip/hip_runtime.h>
#include <math.h>

#define TT 512
#define DPOI 256
#define DIN 260
#define DHID 356
#define DOUTD 512
#define G3 1536

// GRU partition: 8 worker blocks x 1024 threads, 64 hidden units per block.
// Cross-block comm: agent-scope 4-byte self-validating payloads
// {bf16 h | 16-bit step tag} (single-copy-atomic dword). Consumers use
// phase-staggered 2-deep pipelined polling (samples every ~RT/2 instead of
// every RT). REGULAR launch (no cooperative): protocol needs no grid sync —
// tags are monotone, 8 blocks on an empty device are co-resident, and the
// spin budget bounds the pathological case.
#define GB 8
#define HU (DOUTD / GB)      // 64 hidden units per block
#define NRR (3 * HU)         // 192 w_hh rows per block
#define NPAY DOUTD           // 512 dword payload units per step

// ---------------- fused pre-kernel: features + LN + MLP1 + MLP2 + gi ----------------
// One block per timestep t; xn/h1/x2 never touch global memory.
__global__ __launch_bounds__(512)
void pre_kernel(const int* __restrict__ idx, const float* __restrict__ timef,
                const float* __restrict__ latlon, const float* __restrict__ emb,
                const float* __restrict__ lnw, const float* __restrict__ lnb,
                const float* __restrict__ w1, const float* __restrict__ b1,
                const float* __restrict__ w2, const float* __restrict__ b2,
                const float* __restrict__ wih, const float* __restrict__ bih,
                float* __restrict__ gi, unsigned* __restrict__ hcz) {
    int t = blockIdx.x;
    int tid = threadIdx.x;           // 512 threads
    int wave = tid >> 6, lane = tid & 63;

    __shared__ float xl[DIN];
    __shared__ float h1l[DHID];
    __shared__ alignas(16) float x2l[DPOI];
    __shared__ float red[8];
    __shared__ float mu_s, rs_s;

    // zero this block's slice of hcomm step-tags (512 dwords per block)
    hcz[(size_t)t * 512 + tid] = 0u;

    // --- features (redundant per thread; only tid<4 consume) ---
    float tv = fminf(fmaxf(timef[t], 0.f), 1.f);
    const float TWO_PI = 6.28318530717958647692f;
    float f0 = sinf(TWO_PI * tv);
    float f1 = cosf(TWO_PI * tv);
    float f2 = 0.f, f3 = 0.f;
    if (t > 0) {
        float tp = fminf(fmaxf(timef[t - 1], 0.f), 1.f);
        float d = tv - tp;
        d = d - floorf(d);          // jnp.mod(x, 1.0)
        f2 = log1pf(d * 24.f);
        int i0 = idx[t - 1], i1 = idx[t];
        float la0 = latlon[2 * (size_t)i0], lo0 = latlon[2 * (size_t)i0 + 1];
        float la1 = latlon[2 * (size_t)i1], lo1 = latlon[2 * (size_t)i1 + 1];
        const float D2R = 0.01745329251994329577f;
        float lat1 = fminf(fmaxf(la0, -90.f), 90.f) * D2R;
        float lon1 = fminf(fmaxf(lo0, -180.f), 180.f) * D2R;
        float lat2 = fminf(fmaxf(la1, -90.f), 90.f) * D2R;
        float lon2 = fminf(fmaxf(lo1, -180.f), 180.f) * D2R;
        float dlat = (lat2 - lat1) * 0.5f, dlon = (lon2 - lon1) * 0.5f;
        float sdlat = sinf(dlat), sdlon = sinf(dlon);
        float a = sdlat * sdlat +
                  fminf(fmaxf(cosf(lat1), -1.f), 1.f) * fminf(fmaxf(cosf(lat2), -1.f), 1.f) * sdlon * sdlon;
        float aa = fminf(fmaxf(a, 0.f), 1.f);
        float bb = fminf(fmaxf(1.f - a, 1e-12f), 1.f);
        float cc = 2.f * atan2f(sqrtf(aa), sqrtf(bb));
        f3 = log1pf(6371.0088f * cc);
    }
    float fv = (tid == 0) ? f0 : (tid == 1) ? f1 : (tid == 2) ? f2 : f3;

    float v0 = (tid < 256) ? emb[(size_t)idx[t] * DPOI + tid] : 0.f;
    float v1 = (tid < 4) ? fv : 0.f;

    // --- layernorm over 260 elements (8-wave reduce; waves 4-7 contribute 0) ---
    float s = v0 + v1;
    for (int o = 32; o; o >>= 1) s += __shfl_down(s, o, 64);
    if (lane == 0) red[wave] = s;
    __syncthreads();
    if (tid == 0) {
        float mm = 0.f;
        for (int i = 0; i < 8; ++i) mm += red[i];
        mu_s = mm * (1.f / 260.f);
    }
    __syncthreads();
    float mu = mu_s;
    float d0 = (tid < 256) ? (v0 - mu) : 0.f;
    float d1 = (tid < 4) ? (v1 - mu) : 0.f;
    float sq = d0 * d0 + d1 * d1;
    for (int o = 32; o; o >>= 1) sq += __shfl_down(sq, o, 64);
    __syncthreads();
    if (lane == 0) red[wave] = sq;
    __syncthreads();
    if (tid == 0) {
        float vv = 0.f;
        for (int i = 0; i < 8; ++i) vv += red[i];
        rs_s = rsqrtf(vv * (1.f / 260.f) + 1e-5f);
    }
    __syncthreads();
    float rs = rs_s;
    if (tid < 256) xl[tid] = d0 * rs * lnw[tid] + lnb[tid];
    if (tid < 4)   xl[256 + tid] = d1 * rs * lnw[256 + tid] + lnb[256 + tid];
    __syncthreads();

    // --- mlp1: x @ w1 + b1, gelu -> h1 (LDS) ---
    if (tid < DHID) {
        float acc = b1[tid];
        #pragma unroll 4
        for (int k = 0; k < DIN; ++k) acc = fmaf(xl[k], w1[k * DHID + tid], acc);
        h1l[tid] = 0.5f * acc * (1.f + erff(acc * 0.70710678118654752440f));
    }
    __syncthreads();

    // --- mlp2: h1 @ w2 + b2 -> x2 (LDS) ---
    if (tid < DPOI) {
        float acc = b2[tid];
        #pragma unroll 4
        for (int k = 0; k < DHID; ++k) acc = fmaf(h1l[k], w2[k * DPOI + tid], acc);
        x2l[tid] = acc;
    }
    __syncthreads();

    // --- gi: x2 @ w_ih.T + b_ih (1536 rows over 8 waves) ---
    float4 xv = ((const float4*)x2l)[lane];
    for (int r = wave; r < G3; r += 8) {
        float4 wv = ((const float4*)(wih + (size_t)r * DPOI))[lane];
        float sd = xv.x * wv.x + xv.y * wv.y + xv.z * wv.z + xv.w * wv.w;
        for (int o = 32; o; o >>= 1) sd += __shfl_down(sd, o, 64);
        if (lane == 0) gi[(size_t)t * G3 + r] = sd + bih[r];
    }
}

// ---------------- GRU scan: 4B tagged payloads + staggered pipelined polling ----------------
__global__ __launch_bounds__(1024)
void gru_kernel(const float* __restrict__ gi, const float* __restrict__ whh,
                const float* __restrict__ bhh, float* __restrict__ hs,
                unsigned* __restrict__ hcomm) {
    __shared__ alignas(16) float hprev[DOUTD];   // 2 KB
    __shared__ float gsum[NRR];                  // 768 B

    int b = blockIdx.x;        // 0..7
    int tid = threadIdx.x;     // 0..1023
    int wave = tid >> 6, lane = tid & 63;
    int jbase = b * HU;
    int g4 = lane >> 4, l4 = lane & 15;
    int rr0 = wave * 12 + g4 * 3;      // this lane-group's 3 rows

    // --- W_hh fragments -> f32 registers. Lane covers k = m*64 + l4*4 + {0..3} ---
    float4 wf0[8], wf1[8], wf2[8];
    float bl0, bl1, bl2;
    {
        int r0 = rr0, r1 = rr0 + 1, r2 = rr0 + 2;
        const float4* p0 = (const float4*)(whh + (size_t)((r0 >> 6) * DOUTD + jbase + (r0 & 63)) * DOUTD);
        const float4* p1 = (const float4*)(whh + (size_t)((r1 >> 6) * DOUTD + jbase + (r1 & 63)) * DOUTD);
        const float4* p2 = (const float4*)(whh + (size_t)((r2 >> 6) * DOUTD + jbase + (r2 & 63)) * DOUTD);
        #pragma unroll
        for (int m = 0; m < 8; ++m) {
            wf0[m] = p0[m * 16 + l4];
            wf1[m] = p1[m * 16 + l4];
            wf2[m] = p2[m * 16 + l4];
        }
        bl0 = bhh[(r0 >> 6) * DOUTD + jbase + (r0 & 63)];
        bl1 = bhh[(r1 >> 6) * DOUTD + jbase + (r1 & 63)];
        bl2 = bhh[(r2 >> 6) * DOUTD + jbase + (r2 & 63)];
    }
    if (tid < DOUTD) hprev[tid] = 0.f;
    __syncthreads();

    const float4* hp4 = (const float4*)hprev;
    long budget = 3000;               // lifetime re-entry budget (deadlock -> numeric fail)

    // gi prefetch registers (gate wave only), one step ahead; own h in register.
    float gir = 0.f, giz = 0.f, gin = 0.f, hreg = 0.f;
    if (tid < HU) {
        int j = jbase + tid;
        gir = gi[j];
        giz = gi[DOUTD + j];
        gin = gi[2 * DOUTD + j];
    }

    for (int s = 0; s < TT; ++s) {
        unsigned pa = 0, pb = 0;
        if (s > 0) {
            // waves 4..11 poll: wave (4+wsrc) covers producer block wsrc's 64
            // units; the wave matching our own block skips (self-published).
            if (wave >= 4 && wave < 12 && (wave - 4) != b) {
                int u = ((wave - 4) << 6) + lane;
                const unsigned* ap = hcomm + (size_t)(s - 1) * NPAY + u;
                unsigned tag = (unsigned)s & 0xffffu;   // producer stored ((s-1)+1)
                // prime slot A
                asm volatile("global_load_dword %0, %1, off sc0 sc1"
                             : "=v"(pa) : "v"(ap) : "memory");
                // stagger ~RT/2: dependent FMA chain (~1000 cy)
                float xx = (float)(lane + 1) * 1e-6f;
                #pragma unroll
                for (int q = 0; q < 256; ++q) xx = fmaf(xx, 1.0000002f, 1.1920929e-7f);
                // prime slot B (chain feeds in as dummy input -> ordered after spin)
                asm volatile("global_load_dword %0, %1, off sc0 sc1"
                             : "=v"(pb) : "v"(ap), "v"(xx) : "memory");
                // 2-deep round-robin pipelined poll; tag-gated; bounded.
                do {
                    unsigned tmp; int scnt;
                    asm volatile(
                        "s_movk_i32 %[cnt], 64\n\t"
                        "1:\n\t"
                        "s_waitcnt vmcnt(1)\n\t"
                        "v_and_b32 %[t], 0xffff, %[pa]\n\t"
                        "v_cmp_ne_u32 vcc, %[tag], %[t]\n\t"
                        "s_cbranch_vccz 9f\n\t"
                        "global_load_dword %[pa], %[ptr], off sc0 sc1\n\t"
                        "s_waitcnt vmcnt(1)\n\t"
                        "v_and_b32 %[t], 0xffff, %[pb]\n\t"
                        "v_cmp_ne_u32 vcc, %[tag], %[t]\n\t"
                        "s_cbranch_vccz 8f\n\t"
                        "global_load_dword %[pb], %[ptr], off sc0 sc1\n\t"
                        "s_sub_u32 %[cnt], %[cnt], 1\n\t"
                        "s_cmp_lg_u32 %[cnt], 0\n\t"
                        "s_cbranch_scc1 1b\n\t"
                        "s_branch 9f\n\t"
                        "8:\n\t"
                        "v_mov_b32 %[pa], %[pb]\n\t"
                        "9:\n\t"
                        : [pa]"+v"(pa), [pb]"+v"(pb), [t]"=&v"(tmp), [cnt]"=&s"(scnt)
                        : [ptr]"v"(ap), [tag]"s"(tag)
                        : "vcc", "scc", "memory");
                    if ((pa & 0xffffu) == tag) break;
                } while (--budget > 0);
                hprev[u] = __uint_as_float(pa & 0xffff0000u);
            }
            __syncthreads();   // barrier A: full h_{s-1}; implicit vmcnt(0) drains strays
            asm volatile("" :: "v"(pa), "v"(pb));   // keep slot regs reserved past drain
        }

        // matvec: 192 rows; wave w, lane-group g4 -> rows rr0..rr0+2, 16-lane
        // k-split, 96 FMAs/lane, 4-stage xor-reduce within the 16-lane group.
        float a0 = 0.f, a1 = 0.f, a2 = 0.f;
        #pragma unroll
        for (int m = 0; m < 8; ++m) {
            float4 h4 = hp4[m * 16 + l4];
            a0 = fmaf(wf0[m].x, h4.x, a0); a0 = fmaf(wf0[m].y, h4.y, a0);
            a0 = fmaf(wf0[m].z, h4.z, a0); a0 = fmaf(wf0[m].w, h4.w, a0);
            a1 = fmaf(wf1[m].x, h4.x, a1); a1 = fmaf(wf1[m].y, h4.y, a1);
            a1 = fmaf(wf1[m].z, h4.z, a1); a1 = fmaf(wf1[m].w, h4.w, a1);
            a2 = fmaf(wf2[m].x, h4.x, a2); a2 = fmaf(wf2[m].y, h4.y, a2);
            a2 = fmaf(wf2[m].z, h4.z, a2); a2 = fmaf(wf2[m].w, h4.w, a2);
        }
        #pragma unroll
        for (int o = 1; o < 16; o <<= 1) {
            a0 += __shfl_xor(a0, o, 64);
            a1 += __shfl_xor(a1, o, 64);
            a2 += __shfl_xor(a2, o, 64);
        }
        if (l4 == 0) {
            gsum[rr0]     = a0 + bl0;
            gsum[rr0 + 1] = a1 + bl1;
            gsum[rr0 + 2] = a2 + bl2;
        }
        __syncthreads();       // barrier B: gsum complete; all hprev reads done

        if (tid < HU) {        // gate wave: full 64 lanes, one unit each
            float gr  = gir + gsum[tid];
            float gz  = giz + gsum[HU + tid];
            float ghn = gsum[2 * HU + tid];
            float r = __builtin_amdgcn_rcpf(1.f + __expf(-gr));
            float z = __builtin_amdgcn_rcpf(1.f + __expf(-gz));
            float xt = gin + r * ghn;
            float n = 1.f - 2.f * __builtin_amdgcn_rcpf(__expf(2.f * xt) + 1.f);
            float hn = (1.f - z) * n + z * hreg;
            hreg = hn;
            // publish FIRST: {bf16 h | 16-bit tag}, 64 lanes coalesced (1 line)
            unsigned ub = __float_as_uint(hn);
            ub += 0x7fffu + ((ub >> 16) & 1u);        // RNE f32 -> bf16
            unsigned pay = (ub & 0xffff0000u) | ((unsigned)(s + 1) & 0xffffu);
            __hip_atomic_store(&hcomm[(size_t)s * NPAY + jbase + tid], pay,
                               __ATOMIC_RELAXED, __HIP_MEMORY_SCOPE_AGENT);
            int j = jbase + tid;
            hs[(size_t)s * DOUTD + j] = hn;   // full-f32 copy for the attn epilogue
            hprev[j] = hn;                    // self-publish own chunk
            if (s + 1 < TT) {                 // prefetch next step's gi
                const float* gn = gi + (size_t)(s + 1) * G3;
                gir = gn[j]; giz = gn[DOUTD + j]; gin = gn[2 * DOUTD + j];
            }
        }
    }
}

// ---------------- attention epilogue ----------------
__global__ void attn_kernel(const float* __restrict__ hs, const float* __restrict__ q,
                            const float* __restrict__ log_lam, float* __restrict__ out) {
    int tid = threadIdx.x;   // 512
    int wave = tid >> 6, lane = tid & 63;
    __shared__ float sc[TT];
    __shared__ float at[TT];
    __shared__ float red[8];
    __shared__ float red2[8];
    __shared__ float denom_s, mx_s;

    const float qscale = 0.04419417382415921757f;  // 1/sqrt(512)
    for (int r = wave; r < TT; r += 8) {
        float acc = 0.f;
        #pragma unroll
        for (int m = 0; m < 8; ++m) {
            int k = lane + 64 * m;
            acc = fmaf(hs[(size_t)r * DOUTD + k], q[k], acc);
        }
        for (int o = 32; o; o >>= 1) acc += __shfl_down(acc, o, 64);
        if (lane == 0) sc[r] = acc * qscale;
    }
    __syncthreads();
    float lam = fmaxf(expf(log_lam[0]), 1e-4f);
    float s_i = sc[tid] - lam * (float)(TT - 1 - tid);

    float mval = s_i;
    for (int o = 32; o; o >>= 1) mval = fmaxf(mval, __shfl_down(mval, o, 64));
    if (lane == 0) red[wave] = mval;
    __syncthreads();
    if (tid == 0) {
        float mm = red[0];
        for (int i = 1; i < 8; ++i) mm = fmaxf(mm, red[i]);
        mx_s = mm;
    }
    __syncthreads();
    float e = expf(s_i - mx_s);
    float ssum = e;
    for (int o = 32; o; o >>= 1) ssum += __shfl_down(ssum, o, 64);
    if (lane == 0) red2[wave] = ssum;
    __syncthreads();
    if (tid == 0) {
        float dsum = 0.f;
        for (int i = 0; i < 8; ++i) dsum += red2[i];
        denom_s = dsum;
    }
    __syncthreads();
    float attn = e / denom_s;
    out[DOUTD + tid] = attn;     // output 1: attn (T,)
    at[tid] = attn;
    __syncthreads();
    float acc = 0.f;
    for (int i = 0; i < TT; ++i) acc = fmaf(at[i], hs[(size_t)i * DOUTD + tid], acc);
    out[tid] = acc;              // output 0: summary (1, 512)
}

extern "C" void kernel_launch(void* const* d_in, const int* in_sizes, int n_in,
                              void* d_out, int out_size, void* d_ws, size_t ws_size,
                              hipStream_t stream) {
    const int*   idx    = (const int*)d_in[0];
    const float* timef  = (const float*)d_in[1];
    const float* emb    = (const float*)d_in[2];
    const float* latlon = (const float*)d_in[3];
    const float* lnw    = (const float*)d_in[4];
    const float* lnb    = (const float*)d_in[5];
    const float* w1     = (const float*)d_in[6];
    const float* b1     = (const float*)d_in[7];
    const float* w2     = (const float*)d_in[8];
    const float* b2     = (const float*)d_in[9];
    const float* wih    = (const float*)d_in[10];  // (1536, 256)
    const float* whh    = (const float*)d_in[11];  // (1536, 512)
    const float* bih    = (const float*)d_in[12];  // (1536,)
    const float* bhh    = (const float*)d_in[13];  // (1536,)
    const float* q      = (const float*)d_in[14];
    const float* loglam = (const float*)d_in[15];
    float* out = (float*)d_out;

    unsigned* hcomm = (unsigned*)d_ws;                       // 512*512 dwords (1 MB)
    float* gi = (float*)(hcomm + (size_t)TT * NPAY);         // 512*1536 = 786432
    float* hs = gi + (size_t)TT * G3;                        // 512*512 = 262144

    pre_kernel<<<TT, 512, 0, stream>>>(idx, timef, latlon, emb, lnw, lnb,
                                       w1, b1, w2, b2, wih, bih, gi, hcomm);
    gru_kernel<<<GB, 1024, 0, stream>>>(gi, whh, bhh, hs, hcomm);
    attn_kernel<<<1, TT, 0, stream>>>(hs, q, loglam, out);
}